// Round 2
// baseline (3311.189 us; speedup 1.0000x reference)
//
#include <hip/hip_runtime.h>

// BiMPM on MI355X. Round 2: all inputs/outputs are fp32 (per reference dtypes).
// MFMA GEMMs use bf16 hi+lo splitting of both operands (3 MFMAs per K-chunk)
// for ~1e-5 relative accuracy. Per-chain single-workgroup LSTM scan kernels
// keep Whh hi/lo fragments in registers across all 128 steps; h is carried in
// LDS as bf16 hi+lo. Branch + head kernels are plain fp32.

#define Bz 16
#define Sz 128
#define Hz 100
#define Gz 400      // 4H
#define NT 25       // Gz/16 n-tiles
#define NBK 7       // ceil(25/4) n-tile blocks per t
#define EPSV 1e-8f

typedef __attribute__((ext_vector_type(4))) float floatx4;
typedef __attribute__((ext_vector_type(8))) __bf16 bf16x8;

union FragU { bf16x8 v; unsigned u[4]; unsigned short s[8]; };

__device__ __forceinline__ float bf2f(unsigned short h) {
  unsigned u = ((unsigned)h) << 16;
  return __builtin_bit_cast(float, u);
}
__device__ __forceinline__ unsigned short f2bf(float x) {
  unsigned u = __builtin_bit_cast(unsigned, x);
  u = u + 0x7FFFu + ((u >> 16) & 1u);   // RNE
  return (unsigned short)(u >> 16);
}
__device__ __forceinline__ float sigf(float x) { return 1.0f / (1.0f + __expf(-x)); }
__device__ __forceinline__ float tanh_fast(float x) { return 1.0f - 2.0f / (__expf(2.0f * x) + 1.0f); }

// ---------------- projection GEMM: out[t][b][g] = A[b][t'] . W[g] + bias[g] ----
struct ProjChain {
  const int* ids;       // non-null -> gather rows from emb
  const float* emb;     // V x K fp32
  const float* src;     // B x S x K fp32 (if ids == nullptr)
  const float* W;       // G x K fp32 (row-major)
  const float* bias;    // G fp32
  float* out;           // S x B x G fp32 (time-major)
  int rev;
};
struct Proj8 { ProjChain c[8]; };

__global__ __launch_bounds__(256) void k_proj(Proj8 P, int K, int ksteps) {
  int bx = blockIdx.x;
  int c = bx / (Sz * NBK);
  int rem = bx % (Sz * NBK);
  int t = rem / NBK;
  int nb = rem % NBK;
  int wave = threadIdx.x >> 6;
  int ntile = nb * 4 + wave;
  if (ntile >= NT) return;
  int lane = threadIdx.x & 63;
  int ml = lane & 15;   // A: m (=batch) row; B: n (=g) col
  int qd = lane >> 4;

  const ProjChain ch = P.c[c];
  int tp = ch.rev ? (Sz - 1 - t) : t;

  const float* arow = ch.ids ? (ch.emb + (long)ch.ids[ml * Sz + tp] * K)
                             : (ch.src + ((long)ml * Sz + tp) * K);
  const float* wrow = ch.W + (long)(ntile * 16 + ml) * K;

  floatx4 acc = {0.f, 0.f, 0.f, 0.f};
  for (int ks = 0; ks < ksteps; ++ks) {
    int k0 = ks * 32 + qd * 8;
    FragU ahi, alo, whi, wlo;
#pragma unroll
    for (int j = 0; j < 8; ++j) {
      int k = k0 + j;
      float xv = (k < K) ? arow[k] : 0.f;
      float wv = (k < K) ? wrow[k] : 0.f;
      unsigned short xh = f2bf(xv);
      ahi.s[j] = xh; alo.s[j] = f2bf(xv - bf2f(xh));
      unsigned short wh = f2bf(wv);
      whi.s[j] = wh; wlo.s[j] = f2bf(wv - bf2f(wh));
    }
    acc = __builtin_amdgcn_mfma_f32_16x16x32_bf16(ahi.v, whi.v, acc, 0, 0, 0);
    acc = __builtin_amdgcn_mfma_f32_16x16x32_bf16(alo.v, whi.v, acc, 0, 0, 0);
    acc = __builtin_amdgcn_mfma_f32_16x16x32_bf16(ahi.v, wlo.v, acc, 0, 0, 0);
  }
  int g = ntile * 16 + ml;
  float bv = ch.bias[g];
  float* outp = ch.out + (long)t * Bz * Gz + g;
#pragma unroll
  for (int r = 0; r < 4; ++r) {
    int brow = qd * 4 + r;   // C/D: row(M=batch)=qd*4+reg, col(N=g)=lane&15
    outp[brow * Gz] = acc[r] + bv;
  }
}

// ---------------- LSTM scan: one workgroup per chain --------------------------
struct LstmChain {
  const float* xin;     // S x B x G  (x@Wih.T + b, time-major)
  const float* Whh;     // G x H fp32
  float* hout;          // B x S x H fp32 (rev chains stored re-reversed)
  int rev;
};
struct Lstm8 { LstmChain c[8]; };

#define ZS 404    // z row stride
#define HSTR 136  // h row stride in bf16 elems (272B, 16B multiple)

__global__ __launch_bounds__(1024) void k_lstm(Lstm8 P) {
  __shared__ float z[Bz * ZS];
  __shared__ float cst[Bz * Hz];
  __shared__ __align__(16) unsigned short hhi[Bz * HSTR];
  __shared__ __align__(16) unsigned short hlo[Bz * HSTR];

  const LstmChain ch = P.c[blockIdx.x];
  int tid = threadIdx.x;
  int wid = tid >> 6;
  int lane = tid & 63;
  int nl = lane & 15;
  int qd = lane >> 4;

  for (int i = tid; i < Bz * Hz; i += 1024) cst[i] = 0.f;
  for (int i = tid; i < Bz * HSTR; i += 1024) { hhi[i] = 0; hlo[i] = 0; }
  __syncthreads();

  // Whh hi/lo B-fragments in registers for the whole scan: tiles {wid, wid+16}
  int nt0 = wid, nt1 = wid + 16;
  int ntcnt = (nt1 < NT) ? 2 : 1;
  FragU wfh[2][4], wfl[2][4];
  for (int ti = 0; ti < ntcnt; ++ti) {
    int nt = ti ? nt1 : nt0;
    const float* wrow = ch.Whh + (long)(nt * 16 + nl) * Hz;
#pragma unroll
    for (int ks = 0; ks < 4; ++ks) {
      int k0 = ks * 32 + qd * 8;
#pragma unroll
      for (int j = 0; j < 8; ++j) {
        int k = k0 + j;
        float wv = (k < Hz) ? wrow[k] : 0.f;
        unsigned short wh = f2bf(wv);
        wfh[ti][ks].s[j] = wh;
        wfl[ti][ks].s[j] = f2bf(wv - bf2f(wh));
      }
    }
  }

  // prefetch xin for t=0
  floatx4 xc[2];
  for (int ti = 0; ti < ntcnt; ++ti) {
    int g = (ti ? nt1 : nt0) * 16 + nl;
#pragma unroll
    for (int r = 0; r < 4; ++r) xc[ti][r] = ch.xin[(qd * 4 + r) * Gz + g];
  }

  for (int t = 0; t < Sz; ++t) {
    floatx4 xn[2];
    if (t + 1 < Sz) {
      const float* xp = ch.xin + (long)(t + 1) * Bz * Gz;
      for (int ti = 0; ti < ntcnt; ++ti) {
        int g = (ti ? nt1 : nt0) * 16 + nl;
#pragma unroll
        for (int r = 0; r < 4; ++r) xn[ti][r] = xp[(qd * 4 + r) * Gz + g];
      }
    }
    floatx4 acc[2];
    for (int ti = 0; ti < ntcnt; ++ti) acc[ti] = xc[ti];

#pragma unroll
    for (int ks = 0; ks < 4; ++ks) {
      int k0 = ks * 32 + qd * 8;
      FragU ah, al;
      ah.v = *(const bf16x8*)(&hhi[nl * HSTR + k0]);
      al.v = *(const bf16x8*)(&hlo[nl * HSTR + k0]);
      for (int ti = 0; ti < ntcnt; ++ti) {
        acc[ti] = __builtin_amdgcn_mfma_f32_16x16x32_bf16(ah.v, wfh[ti][ks].v, acc[ti], 0, 0, 0);
        acc[ti] = __builtin_amdgcn_mfma_f32_16x16x32_bf16(al.v, wfh[ti][ks].v, acc[ti], 0, 0, 0);
        acc[ti] = __builtin_amdgcn_mfma_f32_16x16x32_bf16(ah.v, wfl[ti][ks].v, acc[ti], 0, 0, 0);
      }
    }
    for (int ti = 0; ti < ntcnt; ++ti) {
      int g = (ti ? nt1 : nt0) * 16 + nl;
#pragma unroll
      for (int r = 0; r < 4; ++r) z[(qd * 4 + r) * ZS + g] = acc[ti][r];
    }
    __syncthreads();

    int s_store = ch.rev ? (Sz - 1 - t) : t;
#pragma unroll
    for (int ii = 0; ii < 2; ++ii) {
      int item = tid + ii * 1024;
      if (item < Bz * Hz) {
        int b = item / Hz;
        int j = item % Hz;
        float zi = z[b * ZS + j];
        float zf = z[b * ZS + Hz + j];
        float zg = z[b * ZS + 2 * Hz + j];
        float zo = z[b * ZS + 3 * Hz + j];
        float cold = cst[item];
        float cnew = sigf(zf) * cold + sigf(zi) * tanh_fast(zg);
        float h = sigf(zo) * tanh_fast(cnew);
        cst[item] = cnew;
        unsigned short hh = f2bf(h);
        hhi[b * HSTR + j] = hh;
        hlo[b * HSTR + j] = f2bf(h - bf2f(hh));
        ch.hout[((long)b * Sz + s_store) * Hz + j] = h;
      }
    }
    __syncthreads();
    for (int ti = 0; ti < ntcnt; ++ti) xc[ti] = xn[ti];
  }
}

// ---------------- cosine attention ------------------------------------------
__global__ __launch_bounds__(256) void k_att(const float* pv, const float* hv, float* att) {
  int bx = blockIdx.x;          // b*64 + pt*8 + qt
  int b = bx >> 6;
  int pt = (bx >> 3) & 7;
  int qt = bx & 7;
  __shared__ float ps[16 * Hz];
  __shared__ float hs[16 * Hz];
  int tid = threadIdx.x;
  for (int i = tid; i < 16 * Hz; i += 256) {
    int r = i / Hz, h = i % Hz;
    ps[i] = pv[((long)b * Sz + pt * 16 + r) * Hz + h];
    hs[i] = hv[((long)b * Sz + qt * 16 + r) * Hz + h];
  }
  __syncthreads();
  int p = tid >> 4, q = tid & 15;
  const float* pr = &ps[p * Hz];
  const float* hr = &hs[q * Hz];
  float pq = 0.f, pp = 0.f, qq = 0.f;
#pragma unroll 4
  for (int h = 0; h < Hz; ++h) {
    float a = pr[h], bb = hr[h];
    pq += a * bb; pp += a * a; qq += bb * bb;
  }
  float denom = fmaxf(sqrtf(pp) * sqrtf(qq), EPSV);
  att[((long)b * Sz + pt * 16 + p) * Sz + qt * 16 + q] = pq / denom;
}

// ---------------- attention features (mean/max, both sides) ------------------
__global__ __launch_bounds__(128) void k_feats(const float* att, const float* pv, const float* hv,
                                               float* mean_h, float* mean_p,
                                               float* max_h, float* max_p) {
  int bx = blockIdx.x;
  int mode = bx / (Bz * Sz);    // 0: rows (h-side), 1: cols (p-side)
  int rem = bx % (Bz * Sz);
  int b = rem / Sz;
  int r = rem % Sz;
  __shared__ float arow[Sz];
  int tid = threadIdx.x;
  if (mode == 0) arow[tid] = att[((long)b * Sz + r) * Sz + tid];
  else           arow[tid] = att[((long)b * Sz + tid) * Sz + r];
  __syncthreads();
  float asum = 0.f;
  for (int k = 0; k < Sz; ++k) asum += arow[k];
  const float* src = (mode == 0) ? hv : pv;
  if (tid < Hz) {
    float acc = 0.f, mx = -1e30f;
    for (int k = 0; k < Sz; ++k) {
      float a = arow[k];
      float v = src[((long)b * Sz + k) * Hz + tid];
      float pr = a * v;
      acc += pr;
      mx = fmaxf(mx, pr);
    }
    float mean = acc / fmaxf(asum, EPSV);
    long o = ((long)b * Sz + r) * Hz + tid;
    if (mode == 0) { mean_h[o] = mean; max_h[o] = mx; }
    else           { mean_p[o] = mean; max_p[o] = mx; }
  }
}

// ---------------- multi-perspective match ------------------------------------
struct MatchDesc {
  const float* v1;      // B x S x H
  const float* v2;      // base ptr; addr = v2 + b*S*H + s*v2_sstride
  int v2_sstride;       // Hz for full, 0 for broadcast
  const float* w;       // L x H fp32
  float* out;           // MV base (stride 120)
  int out_off;
};
struct Match6 { MatchDesc d[6]; };

__global__ __launch_bounds__(256) void k_match(Match6 M) {
  int inst = blockIdx.x / 160;
  int idx = (blockIdx.x % 160) * 256 + threadIdx.x;   // 160*256 = B*S*L
  int l = idx % 20;
  int s = (idx / 20) % Sz;
  int b = idx / (20 * Sz);
  MatchDesc d = M.d[inst];
  const float* v1 = d.v1 + ((long)b * Sz + s) * Hz;
  const float* v2 = d.v2 + (long)b * Sz * Hz + (long)s * d.v2_sstride;
  const float* wr = d.w + l * Hz;
  float num = 0.f, n1 = 0.f, n2 = 0.f;
#pragma unroll 4
  for (int h = 0; h < Hz; ++h) {
    float w = wr[h];
    float ws = w * w;
    float a = v1[h], c = v2[h];
    num += a * c * ws;
    n1  += a * a * ws;
    n2  += c * c * ws;
  }
  float denom = fmaxf(sqrtf(n1) * sqrtf(n2), EPSV);
  d.out[((long)b * Sz + s) * 120 + d.out_off + l] = num / denom;
}

// ---------------- head: highway, fc1+tanh, fc2 -------------------------------
__global__ __launch_bounds__(512) void k_highway(const float* houtB,
                                                 const float* lw, const float* lb,
                                                 const float* gw, const float* gb,
                                                 float* hw) {
  int seq = blockIdx.x >> 4;    // 0: wx (chains 0..3), 1: cx (chains 4..7)
  int b = blockIdx.x & 15;
  __shared__ float xr[Gz];
  int tid = threadIdx.x;
  if (tid < Gz) {
    int seg = tid / Hz, j = tid % Hz;
    int chain = seq * 4 + seg;
    int s_sel = (seg & 1) ? 0 : (Sz - 1);   // fwd hT at s=S-1, bwd hT at s=0
    xr[tid] = houtB[((long)chain * Bz + b) * Sz * Hz + (long)s_sel * Hz + j];
  }
  __syncthreads();
  if (tid < Gz) {
    const float* lwr = lw + (long)tid * Gz;
    const float* gwr = gw + (long)tid * Gz;
    float al = 0.f, ag = 0.f;
#pragma unroll 4
    for (int k = 0; k < Gz; ++k) {
      float x = xr[k];
      al += x * lwr[k];
      ag += x * gwr[k];
    }
    al += lb[tid];
    ag += gb[tid];
    float hlin = fmaxf(al, 0.f);
    float tg = sigf(ag);
    hw[((long)seq * Bz + b) * Gz + tid] = tg * hlin + (1.f - tg) * xr[tid];
  }
}

__global__ __launch_bounds__(256) void k_fc1(const float* hw, const float* w,
                                             const float* bias, float* fc1o) {
  int b = blockIdx.x;
  __shared__ float xc[800];
  int tid = threadIdx.x;
  for (int i = tid; i < 800; i += 256) {
    int seq = i / Gz, j = i % Gz;
    xc[i] = hw[((long)seq * Bz + b) * Gz + j];
  }
  __syncthreads();
  if (tid < 200) {
    const float* wr = w + (long)tid * 800;
    float acc = bias[tid];
#pragma unroll 4
    for (int k = 0; k < 800; ++k) acc += xc[k] * wr[k];
    fc1o[b * 200 + tid] = tanh_fast(acc);
  }
}

__global__ __launch_bounds__(64) void k_fc2(const float* fc1o, const float* w,
                                            const float* bias, float* out) {
  int tid = threadIdx.x;
  if (tid < Bz * 3) {
    int b = tid / 3, c = tid % 3;
    const float* wr = w + c * 200;
    float acc = bias[c];
    for (int k = 0; k < 200; ++k) acc += fc1o[b * 200 + k] * wr[k];
    out[b * 3 + c] = acc;
  }
}

// ---------------- host orchestration -----------------------------------------
extern "C" void kernel_launch(void* const* d_in, const int* in_sizes, int n_in,
                              void* d_out, int out_size, void* d_ws, size_t ws_size,
                              hipStream_t stream) {
  (void)in_sizes; (void)n_in; (void)out_size;

  const int* p_ids  = (const int*)d_in[0];
  const int* h_ids  = (const int*)d_in[1];
  const int* cp_ids = (const int*)d_in[2];
  const int* ch_ids = (const int*)d_in[3];
  const float* word_emb = (const float*)d_in[4];
  const float* char_emb = (const float*)d_in[5];
  const float* ctx_Wih_f = (const float*)d_in[6];
  const float* ctx_Whh_f = (const float*)d_in[7];
  const float* ctx_b_f   = (const float*)d_in[8];
  const float* ctx_Wih_b = (const float*)d_in[9];
  const float* ctx_Whh_b = (const float*)d_in[10];
  const float* ctx_b_b   = (const float*)d_in[11];
  const float* chr_Wih_f = (const float*)d_in[12];
  const float* chr_Whh_f = (const float*)d_in[13];
  const float* chr_b_f   = (const float*)d_in[14];
  const float* chr_Wih_b = (const float*)d_in[15];
  const float* chr_Whh_b = (const float*)d_in[16];
  const float* chr_b_b   = (const float*)d_in[17];
  const float* agg_Wih_f = (const float*)d_in[18];
  const float* agg_Whh_f = (const float*)d_in[19];
  const float* agg_b_f   = (const float*)d_in[20];
  const float* agg_Wih_b = (const float*)d_in[21];
  const float* agg_Whh_b = (const float*)d_in[22];
  const float* agg_b_b   = (const float*)d_in[23];
  const float* mp_w[6] = {
    (const float*)d_in[24], (const float*)d_in[25], (const float*)d_in[26],
    (const float*)d_in[27], (const float*)d_in[28], (const float*)d_in[29]};
  const float* char_w1 = (const float*)d_in[30];
  const float* char_w2 = (const float*)d_in[31];
  const float* hw_lin_w  = (const float*)d_in[32];
  const float* hw_lin_b  = (const float*)d_in[33];
  const float* hw_gate_w = (const float*)d_in[34];
  const float* hw_gate_b = (const float*)d_in[35];
  const float* fc1_w = (const float*)d_in[36];
  const float* fc1_b = (const float*)d_in[37];
  const float* fc2_w = (const float*)d_in[38];
  const float* fc2_b = (const float*)d_in[39];

  const long XIN_CH = (long)Sz * Bz * Gz;     // 819200
  const long HOUT_CH = (long)Bz * Sz * Hz;    // 204800
  const long MV_CH = (long)Bz * Sz * 120;     // 245760
  float* ws = (float*)d_ws;
  float* XIN    = ws;                         // 8 chains (reused phase A -> B)
  float* HOUT_A = XIN + 8 * XIN_CH;
  float* HOUT_B = HOUT_A + 8 * HOUT_CH;
  float* MV     = HOUT_B + 8 * HOUT_CH;       // mv_p, mv_h, cmv_p, cmv_h
  float* ATT    = MV + 4 * MV_CH;
  float* FEAT   = ATT + (long)Bz * Sz * Sz;   // mean_h, mean_p, max_h, max_p
  float* HW     = FEAT + 4 * HOUT_CH;
  float* FC1O   = HW + 2 * Bz * Gz;
  size_t needed = (size_t)((FC1O + Bz * 200) - ws) * 4;
  if (ws_size < needed) return;               // ws too small: fail visibly

  // ---- phase A projections: ctx (word, K=300), chr (char, K=50) ----
  {
    Proj8 pc{};
    const int* idv[4] = {p_ids, p_ids, h_ids, h_ids};
    const float* wv[2] = {ctx_Wih_f, ctx_Wih_b};
    const float* bv[2] = {ctx_b_f, ctx_b_b};
    for (int c = 0; c < 4; ++c) {
      pc.c[c].ids = idv[c]; pc.c[c].emb = word_emb; pc.c[c].src = nullptr;
      pc.c[c].W = wv[c & 1]; pc.c[c].bias = bv[c & 1];
      pc.c[c].out = XIN + c * XIN_CH; pc.c[c].rev = c & 1;
    }
    k_proj<<<4 * Sz * NBK, 256, 0, stream>>>(pc, 300, 10);
  }
  {
    Proj8 pc{};
    const int* idv[4] = {cp_ids, cp_ids, ch_ids, ch_ids};
    const float* wv[2] = {chr_Wih_f, chr_Wih_b};
    const float* bv[2] = {chr_b_f, chr_b_b};
    for (int c = 0; c < 4; ++c) {
      pc.c[c].ids = idv[c]; pc.c[c].emb = char_emb; pc.c[c].src = nullptr;
      pc.c[c].W = wv[c & 1]; pc.c[c].bias = bv[c & 1];
      pc.c[c].out = XIN + (4 + c) * XIN_CH; pc.c[c].rev = c & 1;
    }
    k_proj<<<4 * Sz * NBK, 256, 0, stream>>>(pc, 50, 2);
  }
  // ---- phase A LSTMs: 8 chains in parallel ----
  {
    Lstm8 la{};
    for (int c = 0; c < 8; ++c) {
      la.c[c].xin = XIN + c * XIN_CH;
      la.c[c].Whh = (c < 4) ? ((c & 1) ? ctx_Whh_b : ctx_Whh_f)
                            : ((c & 1) ? chr_Whh_b : chr_Whh_f);
      la.c[c].hout = HOUT_A + c * HOUT_CH;
      la.c[c].rev = c & 1;
    }
    k_lstm<<<8, 1024, 0, stream>>>(la);
  }

  // ---- branch (word fw/bw, char fw/bw) ----
  float* Fmh = FEAT;                // mean_h
  float* Fmp = FEAT + HOUT_CH;      // mean_p
  float* Fxh = FEAT + 2 * HOUT_CH;  // max_h
  float* Fxp = FEAT + 3 * HOUT_CH;  // max_p

  for (int grp = 0; grp < 4; ++grp) {   // 0: word fw, 1: word bw, 2: char fw, 3: char bw
    int word = (grp < 2);
    int fw = !(grp & 1);
    const float* PV = HOUT_A + (word ? 0 : 4 * HOUT_CH) + (fw ? 0 : HOUT_CH);
    const float* HV = HOUT_A + (word ? 0 : 4 * HOUT_CH) + 2 * HOUT_CH + (fw ? 0 : HOUT_CH);
    float* mvp = MV + (word ? 0 : 2 * MV_CH);
    float* mvh = MV + (word ? 0 : 2 * MV_CH) + MV_CH;
    const float* w_full = word ? (fw ? mp_w[0] : mp_w[1]) : (fw ? char_w1 : char_w2);
    const float* w_mean = fw ? mp_w[2] : mp_w[3];
    const float* w_max  = fw ? mp_w[4] : mp_w[5];
    int off = fw ? 0 : 60;
    long bc = fw ? (long)(Sz - 1) * Hz : 0;   // broadcast row: hT position

    k_att<<<Bz * 64, 256, 0, stream>>>(PV, HV, ATT);
    k_feats<<<2 * Bz * Sz, 128, 0, stream>>>(ATT, PV, HV, Fmh, Fmp, Fxh, Fxp);
    Match6 m{};
    m.d[0] = {PV, HV + bc, 0, w_full, mvp, off + 0};
    m.d[1] = {PV, Fmh, Hz, w_mean, mvp, off + 20};
    m.d[2] = {PV, Fxh, Hz, w_max, mvp, off + 40};
    m.d[3] = {HV, PV + bc, 0, w_full, mvh, off + 0};
    m.d[4] = {HV, Fmp, Hz, w_mean, mvh, off + 20};
    m.d[5] = {HV, Fxp, Hz, w_max, mvh, off + 40};
    k_match<<<6 * 160, 256, 0, stream>>>(m);
  }

  // ---- agg projections (fp32 src, K=120) + agg LSTMs ----
  {
    Proj8 pa{};
    for (int c = 0; c < 8; ++c) {
      pa.c[c].ids = nullptr; pa.c[c].emb = nullptr;
      pa.c[c].src = MV + (c >> 1) * MV_CH;
      pa.c[c].W = (c & 1) ? agg_Wih_b : agg_Wih_f;
      pa.c[c].bias = (c & 1) ? agg_b_b : agg_b_f;
      pa.c[c].out = XIN + c * XIN_CH;
      pa.c[c].rev = c & 1;
    }
    k_proj<<<8 * Sz * NBK, 256, 0, stream>>>(pa, 120, 4);
  }
  {
    Lstm8 la{};
    for (int c = 0; c < 8; ++c) {
      la.c[c].xin = XIN + c * XIN_CH;
      la.c[c].Whh = (c & 1) ? agg_Whh_b : agg_Whh_f;
      la.c[c].hout = HOUT_B + c * HOUT_CH;
      la.c[c].rev = c & 1;
    }
    k_lstm<<<8, 1024, 0, stream>>>(la);
  }

  // ---- head ----
  k_highway<<<2 * Bz, 512, 0, stream>>>(HOUT_B, hw_lin_w, hw_lin_b, hw_gate_w, hw_gate_b, HW);
  k_fc1<<<Bz, 256, 0, stream>>>(HW, fc1_w, fc1_b, FC1O);
  k_fc2<<<1, 64, 0, stream>>>(FC1O, fc2_w, fc2_b, (float*)d_out);
}

// Round 3
// 1376.604 us; speedup vs baseline: 2.4053x; 2.4053x over previous
//
#include <hip/hip_runtime.h>

// BiMPM on MI355X. Round 3: k_lstm rebuilt with fully static register indexing
// (round-2's runtime-bound ti-loops demoted all MFMA fragments to scratch ->
// VGPR_Count=40 and 10x slowdown). 2-MFMA split (h hi+lo x W hi) in lstm and
// proj. Phase-B lstm stores only the final h.

#define Bz 16
#define Sz 128
#define Hz 100
#define Gz 400      // 4H
#define NT 25       // Gz/16 n-tiles
#define NBK 7       // ceil(25/4) n-tile blocks per t
#define EPSV 1e-8f

typedef __attribute__((ext_vector_type(4))) float floatx4;
typedef __attribute__((ext_vector_type(8))) __bf16 bf16x8;

union FragU { bf16x8 v; unsigned u[4]; unsigned short s[8]; };

__device__ __forceinline__ float bf2f(unsigned short h) {
  unsigned u = ((unsigned)h) << 16;
  return __builtin_bit_cast(float, u);
}
__device__ __forceinline__ unsigned short f2bf(float x) {
  unsigned u = __builtin_bit_cast(unsigned, x);
  u = u + 0x7FFFu + ((u >> 16) & 1u);   // RNE
  return (unsigned short)(u >> 16);
}
__device__ __forceinline__ float sigf(float x) { return 1.0f / (1.0f + __expf(-x)); }
__device__ __forceinline__ float tanh_fast(float x) { return 1.0f - 2.0f / (__expf(2.0f * x) + 1.0f); }

#define MFMA(a, b, c) __builtin_amdgcn_mfma_f32_16x16x32_bf16((a), (b), (c), 0, 0, 0)

// ---------------- projection GEMM: out[t][b][g] = A[b][t'] . W[g] + bias[g] ----
struct ProjChain {
  const int* ids;       // non-null -> gather rows from emb
  const float* emb;     // V x K fp32
  const float* src;     // B x S x K fp32 (if ids == nullptr)
  const float* W;       // G x K fp32 (row-major)
  const float* bias;    // G fp32
  float* out;           // S x B x G fp32 (time-major)
  int rev;
};
struct Proj8 { ProjChain c[8]; };

__global__ __launch_bounds__(256) void k_proj(Proj8 P, int K, int ksteps) {
  int bx = blockIdx.x;
  int c = bx / (Sz * NBK);
  int rem = bx % (Sz * NBK);
  int t = rem / NBK;
  int nb = rem % NBK;
  int wave = threadIdx.x >> 6;
  int ntile = nb * 4 + wave;
  if (ntile >= NT) return;
  int lane = threadIdx.x & 63;
  int ml = lane & 15;   // A: m (=batch) row; B: n (=g) col
  int qd = lane >> 4;

  const ProjChain ch = P.c[c];
  int tp = ch.rev ? (Sz - 1 - t) : t;

  const float* arow = ch.ids ? (ch.emb + (long)ch.ids[ml * Sz + tp] * K)
                             : (ch.src + ((long)ml * Sz + tp) * K);
  const float* wrow = ch.W + (long)(ntile * 16 + ml) * K;

  floatx4 acc = {0.f, 0.f, 0.f, 0.f};
  for (int ks = 0; ks < ksteps; ++ks) {
    int k0 = ks * 32 + qd * 8;
    FragU ahi, alo, whi;
#pragma unroll
    for (int j = 0; j < 8; ++j) {
      int k = k0 + j;
      float xv = (k < K) ? arow[k] : 0.f;
      float wv = (k < K) ? wrow[k] : 0.f;
      unsigned short xh = f2bf(xv);
      ahi.s[j] = xh; alo.s[j] = f2bf(xv - bf2f(xh));
      whi.s[j] = f2bf(wv);
    }
    acc = MFMA(ahi.v, whi.v, acc);
    acc = MFMA(alo.v, whi.v, acc);
  }
  int g = ntile * 16 + ml;
  float bv = ch.bias[g];
  float* outp = ch.out + (long)t * Bz * Gz + g;
#pragma unroll
  for (int r = 0; r < 4; ++r) {
    int brow = qd * 4 + r;   // C/D: row(M=batch)=qd*4+reg, col(N=g)=lane&15
    outp[brow * Gz] = acc[r] + bv;
  }
}

// ---------------- LSTM scan: one workgroup per chain --------------------------
struct LstmChain {
  const float* xin;     // S x B x G  (x@Wih.T + b, time-major)
  const float* Whh;     // G x H fp32
  float* hout;          // B x S x H fp32 (rev chains stored re-reversed)
  int rev;
  int store_all;        // 1: store h every step; 0: only final h
};
struct Lstm8 { LstmChain c[8]; };

#define ZS 404    // z row stride (floats)
#define HSTR 136  // h row stride in bf16 elems (272B, 16B multiple)

__global__ __launch_bounds__(1024) void k_lstm(Lstm8 P) {
  __shared__ float z[Bz * ZS];
  __shared__ float cst[Bz * Hz];
  __shared__ __align__(16) unsigned short hhi[Bz * HSTR];
  __shared__ __align__(16) unsigned short hlo[Bz * HSTR];

  const LstmChain ch = P.c[blockIdx.x];
  const int tid = threadIdx.x;
  const int wid = tid >> 6;
  const int lane = tid & 63;
  const int nl = lane & 15;
  const int qd = lane >> 4;

  for (int i = tid; i < Bz * Hz; i += 1024) cst[i] = 0.f;
  for (int i = tid; i < Bz * HSTR; i += 1024) { hhi[i] = 0; hlo[i] = 0; }
  __syncthreads();

  const bool has2 = (wid + 16) < NT;      // waves 0..8 own a second tile
  const int g0 = wid * 16 + nl;
  const int g1 = (wid + 16) * 16 + nl;

  // Whh hi fragments in registers for the whole scan (static indexing only)
  FragU w0[4], w1[4];
  {
    const float* wr0 = ch.Whh + (long)g0 * Hz;
    const float* wr1 = ch.Whh + (long)g1 * Hz;
#pragma unroll
    for (int ks = 0; ks < 4; ++ks) {
#pragma unroll
      for (int j = 0; j < 8; ++j) {
        int k = ks * 32 + qd * 8 + j;
        w0[ks].s[j] = f2bf((k < Hz) ? wr0[k] : 0.f);
        w1[ks].s[j] = f2bf((has2 && k < Hz) ? wr1[k] : 0.f);
      }
    }
  }

  // prefetch xin for t=0
  floatx4 xc0, xc1, xn0, xn1;
#pragma unroll
  for (int r = 0; r < 4; ++r) {
    xc0[r] = ch.xin[(qd * 4 + r) * Gz + g0];
    xc1[r] = has2 ? ch.xin[(qd * 4 + r) * Gz + g1] : 0.f;
  }

  for (int t = 0; t < Sz; ++t) {
    if (t + 1 < Sz) {
      const float* xp = ch.xin + (long)(t + 1) * Bz * Gz;
#pragma unroll
      for (int r = 0; r < 4; ++r) {
        xn0[r] = xp[(qd * 4 + r) * Gz + g0];
        xn1[r] = has2 ? xp[(qd * 4 + r) * Gz + g1] : 0.f;
      }
    }
    floatx4 acc0 = xc0, acc1 = xc1;
#pragma unroll
    for (int ks = 0; ks < 4; ++ks) {
      FragU ah, al;
      ah.v = *(const bf16x8*)(&hhi[nl * HSTR + ks * 32 + qd * 8]);
      al.v = *(const bf16x8*)(&hlo[nl * HSTR + ks * 32 + qd * 8]);
      acc0 = MFMA(ah.v, w0[ks].v, acc0);
      acc0 = MFMA(al.v, w0[ks].v, acc0);
      if (has2) {
        acc1 = MFMA(ah.v, w1[ks].v, acc1);
        acc1 = MFMA(al.v, w1[ks].v, acc1);
      }
    }
#pragma unroll
    for (int r = 0; r < 4; ++r) {
      z[(qd * 4 + r) * ZS + g0] = acc0[r];
      if (has2) z[(qd * 4 + r) * ZS + g1] = acc1[r];
    }
    __syncthreads();

    int s_store = ch.rev ? (Sz - 1 - t) : t;
    bool do_store = ch.store_all || (t == Sz - 1);
#pragma unroll
    for (int ii = 0; ii < 2; ++ii) {
      int item = tid + ii * 1024;
      if (item < Bz * Hz) {
        int b = item / Hz;
        int j = item % Hz;
        float zi = z[b * ZS + j];
        float zf = z[b * ZS + Hz + j];
        float zg = z[b * ZS + 2 * Hz + j];
        float zo = z[b * ZS + 3 * Hz + j];
        float cold = cst[item];
        float cnew = sigf(zf) * cold + sigf(zi) * tanh_fast(zg);
        float h = sigf(zo) * tanh_fast(cnew);
        cst[item] = cnew;
        if (do_store) ch.hout[((long)b * Sz + s_store) * Hz + j] = h;
        unsigned short hh = f2bf(h);
        hhi[b * HSTR + j] = hh;
        hlo[b * HSTR + j] = f2bf(h - bf2f(hh));
      }
    }
    __syncthreads();
    xc0 = xn0; xc1 = xn1;
  }
}

// ---------------- cosine attention ------------------------------------------
__global__ __launch_bounds__(256) void k_att(const float* pv, const float* hv, float* att) {
  int bx = blockIdx.x;          // b*64 + pt*8 + qt
  int b = bx >> 6;
  int pt = (bx >> 3) & 7;
  int qt = bx & 7;
  __shared__ float ps[16 * Hz];
  __shared__ float hs[16 * Hz];
  int tid = threadIdx.x;
  for (int i = tid; i < 16 * Hz; i += 256) {
    int r = i / Hz, h = i % Hz;
    ps[i] = pv[((long)b * Sz + pt * 16 + r) * Hz + h];
    hs[i] = hv[((long)b * Sz + qt * 16 + r) * Hz + h];
  }
  __syncthreads();
  int p = tid >> 4, q = tid & 15;
  const float* pr = &ps[p * Hz];
  const float* hr = &hs[q * Hz];
  float pq = 0.f, pp = 0.f, qq = 0.f;
#pragma unroll 4
  for (int h = 0; h < Hz; ++h) {
    float a = pr[h], bb = hr[h];
    pq += a * bb; pp += a * a; qq += bb * bb;
  }
  float denom = fmaxf(sqrtf(pp) * sqrtf(qq), EPSV);
  att[((long)b * Sz + pt * 16 + p) * Sz + qt * 16 + q] = pq / denom;
}

// ---------------- attention features (mean/max, both sides) ------------------
__global__ __launch_bounds__(128) void k_feats(const float* att, const float* pv, const float* hv,
                                               float* mean_h, float* mean_p,
                                               float* max_h, float* max_p) {
  int bx = blockIdx.x;
  int mode = bx / (Bz * Sz);    // 0: rows (h-side), 1: cols (p-side)
  int rem = bx % (Bz * Sz);
  int b = rem / Sz;
  int r = rem % Sz;
  __shared__ float arow[Sz];
  int tid = threadIdx.x;
  if (mode == 0) arow[tid] = att[((long)b * Sz + r) * Sz + tid];
  else           arow[tid] = att[((long)b * Sz + tid) * Sz + r];
  __syncthreads();
  float asum = 0.f;
  for (int k = 0; k < Sz; ++k) asum += arow[k];
  const float* src = (mode == 0) ? hv : pv;
  if (tid < Hz) {
    float acc = 0.f, mx = -1e30f;
    for (int k = 0; k < Sz; ++k) {
      float a = arow[k];
      float v = src[((long)b * Sz + k) * Hz + tid];
      float pr = a * v;
      acc += pr;
      mx = fmaxf(mx, pr);
    }
    float mean = acc / fmaxf(asum, EPSV);
    long o = ((long)b * Sz + r) * Hz + tid;
    if (mode == 0) { mean_h[o] = mean; max_h[o] = mx; }
    else           { mean_p[o] = mean; max_p[o] = mx; }
  }
}

// ---------------- multi-perspective match ------------------------------------
struct MatchDesc {
  const float* v1;      // B x S x H
  const float* v2;      // base ptr; addr = v2 + b*S*H + s*v2_sstride
  int v2_sstride;       // Hz for full, 0 for broadcast
  const float* w;       // L x H fp32
  float* out;           // MV base (stride 120)
  int out_off;
};
struct Match6 { MatchDesc d[6]; };

__global__ __launch_bounds__(256) void k_match(Match6 M) {
  int inst = blockIdx.x / 160;
  int idx = (blockIdx.x % 160) * 256 + threadIdx.x;   // 160*256 = B*S*L
  int l = idx % 20;
  int s = (idx / 20) % Sz;
  int b = idx / (20 * Sz);
  MatchDesc d = M.d[inst];
  const float* v1 = d.v1 + ((long)b * Sz + s) * Hz;
  const float* v2 = d.v2 + (long)b * Sz * Hz + (long)s * d.v2_sstride;
  const float* wr = d.w + l * Hz;
  float num = 0.f, n1 = 0.f, n2 = 0.f;
#pragma unroll 4
  for (int h = 0; h < Hz; ++h) {
    float w = wr[h];
    float ws = w * w;
    float a = v1[h], c = v2[h];
    num += a * c * ws;
    n1  += a * a * ws;
    n2  += c * c * ws;
  }
  float denom = fmaxf(sqrtf(n1) * sqrtf(n2), EPSV);
  d.out[((long)b * Sz + s) * 120 + d.out_off + l] = num / denom;
}

// ---------------- head: highway, fc1+tanh, fc2 -------------------------------
__global__ __launch_bounds__(512) void k_highway(const float* houtB,
                                                 const float* lw, const float* lb,
                                                 const float* gw, const float* gb,
                                                 float* hw) {
  int seq = blockIdx.x >> 4;    // 0: wx (chains 0..3), 1: cx (chains 4..7)
  int b = blockIdx.x & 15;
  __shared__ float xr[Gz];
  int tid = threadIdx.x;
  if (tid < Gz) {
    int seg = tid / Hz, j = tid % Hz;
    int chain = seq * 4 + seg;
    int s_sel = (seg & 1) ? 0 : (Sz - 1);   // fwd hT at s=S-1, bwd hT at s=0
    xr[tid] = houtB[((long)chain * Bz + b) * Sz * Hz + (long)s_sel * Hz + j];
  }
  __syncthreads();
  if (tid < Gz) {
    const float* lwr = lw + (long)tid * Gz;
    const float* gwr = gw + (long)tid * Gz;
    float al = 0.f, ag = 0.f;
#pragma unroll 4
    for (int k = 0; k < Gz; ++k) {
      float x = xr[k];
      al += x * lwr[k];
      ag += x * gwr[k];
    }
    al += lb[tid];
    ag += gb[tid];
    float hlin = fmaxf(al, 0.f);
    float tg = sigf(ag);
    hw[((long)seq * Bz + b) * Gz + tid] = tg * hlin + (1.f - tg) * xr[tid];
  }
}

__global__ __launch_bounds__(256) void k_fc1(const float* hw, const float* w,
                                             const float* bias, float* fc1o) {
  int b = blockIdx.x;
  __shared__ float xc[800];
  int tid = threadIdx.x;
  for (int i = tid; i < 800; i += 256) {
    int seq = i / Gz, j = i % Gz;
    xc[i] = hw[((long)seq * Bz + b) * Gz + j];
  }
  __syncthreads();
  if (tid < 200) {
    const float* wr = w + (long)tid * 800;
    float acc = bias[tid];
#pragma unroll 4
    for (int k = 0; k < 800; ++k) acc += xc[k] * wr[k];
    fc1o[b * 200 + tid] = tanh_fast(acc);
  }
}

__global__ __launch_bounds__(64) void k_fc2(const float* fc1o, const float* w,
                                            const float* bias, float* out) {
  int tid = threadIdx.x;
  if (tid < Bz * 3) {
    int b = tid / 3, c = tid % 3;
    const float* wr = w + c * 200;
    float acc = bias[c];
    for (int k = 0; k < 200; ++k) acc += fc1o[b * 200 + k] * wr[k];
    out[b * 3 + c] = acc;
  }
}

// ---------------- host orchestration -----------------------------------------
extern "C" void kernel_launch(void* const* d_in, const int* in_sizes, int n_in,
                              void* d_out, int out_size, void* d_ws, size_t ws_size,
                              hipStream_t stream) {
  (void)in_sizes; (void)n_in; (void)out_size;

  const int* p_ids  = (const int*)d_in[0];
  const int* h_ids  = (const int*)d_in[1];
  const int* cp_ids = (const int*)d_in[2];
  const int* ch_ids = (const int*)d_in[3];
  const float* word_emb = (const float*)d_in[4];
  const float* char_emb = (const float*)d_in[5];
  const float* ctx_Wih_f = (const float*)d_in[6];
  const float* ctx_Whh_f = (const float*)d_in[7];
  const float* ctx_b_f   = (const float*)d_in[8];
  const float* ctx_Wih_b = (const float*)d_in[9];
  const float* ctx_Whh_b = (const float*)d_in[10];
  const float* ctx_b_b   = (const float*)d_in[11];
  const float* chr_Wih_f = (const float*)d_in[12];
  const float* chr_Whh_f = (const float*)d_in[13];
  const float* chr_b_f   = (const float*)d_in[14];
  const float* chr_Wih_b = (const float*)d_in[15];
  const float* chr_Whh_b = (const float*)d_in[16];
  const float* chr_b_b   = (const float*)d_in[17];
  const float* agg_Wih_f = (const float*)d_in[18];
  const float* agg_Whh_f = (const float*)d_in[19];
  const float* agg_b_f   = (const float*)d_in[20];
  const float* agg_Wih_b = (const float*)d_in[21];
  const float* agg_Whh_b = (const float*)d_in[22];
  const float* agg_b_b   = (const float*)d_in[23];
  const float* mp_w[6] = {
    (const float*)d_in[24], (const float*)d_in[25], (const float*)d_in[26],
    (const float*)d_in[27], (const float*)d_in[28], (const float*)d_in[29]};
  const float* char_w1 = (const float*)d_in[30];
  const float* char_w2 = (const float*)d_in[31];
  const float* hw_lin_w  = (const float*)d_in[32];
  const float* hw_lin_b  = (const float*)d_in[33];
  const float* hw_gate_w = (const float*)d_in[34];
  const float* hw_gate_b = (const float*)d_in[35];
  const float* fc1_w = (const float*)d_in[36];
  const float* fc1_b = (const float*)d_in[37];
  const float* fc2_w = (const float*)d_in[38];
  const float* fc2_b = (const float*)d_in[39];

  const long XIN_CH = (long)Sz * Bz * Gz;     // 819200
  const long HOUT_CH = (long)Bz * Sz * Hz;    // 204800
  const long MV_CH = (long)Bz * Sz * 120;     // 245760
  float* ws = (float*)d_ws;
  float* XIN    = ws;                         // 8 chains (reused phase A -> B)
  float* HOUT_A = XIN + 8 * XIN_CH;
  float* HOUT_B = HOUT_A + 8 * HOUT_CH;
  float* MV     = HOUT_B + 8 * HOUT_CH;       // mv_p, mv_h, cmv_p, cmv_h
  float* ATT    = MV + 4 * MV_CH;
  float* FEAT   = ATT + (long)Bz * Sz * Sz;   // mean_h, mean_p, max_h, max_p
  float* HW     = FEAT + 4 * HOUT_CH;
  float* FC1O   = HW + 2 * Bz * Gz;
  size_t needed = (size_t)((FC1O + Bz * 200) - ws) * 4;
  if (ws_size < needed) return;               // ws too small: fail visibly

  // ---- phase A projections: ctx (word, K=300), chr (char, K=50) ----
  {
    Proj8 pc{};
    const int* idv[4] = {p_ids, p_ids, h_ids, h_ids};
    const float* wv[2] = {ctx_Wih_f, ctx_Wih_b};
    const float* bv[2] = {ctx_b_f, ctx_b_b};
    for (int c = 0; c < 4; ++c) {
      pc.c[c].ids = idv[c]; pc.c[c].emb = word_emb; pc.c[c].src = nullptr;
      pc.c[c].W = wv[c & 1]; pc.c[c].bias = bv[c & 1];
      pc.c[c].out = XIN + c * XIN_CH; pc.c[c].rev = c & 1;
    }
    k_proj<<<4 * Sz * NBK, 256, 0, stream>>>(pc, 300, 10);
  }
  {
    Proj8 pc{};
    const int* idv[4] = {cp_ids, cp_ids, ch_ids, ch_ids};
    const float* wv[2] = {chr_Wih_f, chr_Wih_b};
    const float* bv[2] = {chr_b_f, chr_b_b};
    for (int c = 0; c < 4; ++c) {
      pc.c[c].ids = idv[c]; pc.c[c].emb = char_emb; pc.c[c].src = nullptr;
      pc.c[c].W = wv[c & 1]; pc.c[c].bias = bv[c & 1];
      pc.c[c].out = XIN + (4 + c) * XIN_CH; pc.c[c].rev = c & 1;
    }
    k_proj<<<4 * Sz * NBK, 256, 0, stream>>>(pc, 50, 2);
  }
  // ---- phase A LSTMs: 8 chains in parallel ----
  {
    Lstm8 la{};
    for (int c = 0; c < 8; ++c) {
      la.c[c].xin = XIN + c * XIN_CH;
      la.c[c].Whh = (c < 4) ? ((c & 1) ? ctx_Whh_b : ctx_Whh_f)
                            : ((c & 1) ? chr_Whh_b : chr_Whh_f);
      la.c[c].hout = HOUT_A + c * HOUT_CH;
      la.c[c].rev = c & 1;
      la.c[c].store_all = 1;
    }
    k_lstm<<<8, 1024, 0, stream>>>(la);
  }

  // ---- branch (word fw/bw, char fw/bw) ----
  float* Fmh = FEAT;                // mean_h
  float* Fmp = FEAT + HOUT_CH;      // mean_p
  float* Fxh = FEAT + 2 * HOUT_CH;  // max_h
  float* Fxp = FEAT + 3 * HOUT_CH;  // max_p

  for (int grp = 0; grp < 4; ++grp) {   // 0: word fw, 1: word bw, 2: char fw, 3: char bw
    int word = (grp < 2);
    int fw = !(grp & 1);
    const float* PV = HOUT_A + (word ? 0 : 4 * HOUT_CH) + (fw ? 0 : HOUT_CH);
    const float* HV = HOUT_A + (word ? 0 : 4 * HOUT_CH) + 2 * HOUT_CH + (fw ? 0 : HOUT_CH);
    float* mvp = MV + (word ? 0 : 2 * MV_CH);
    float* mvh = MV + (word ? 0 : 2 * MV_CH) + MV_CH;
    const float* w_full = word ? (fw ? mp_w[0] : mp_w[1]) : (fw ? char_w1 : char_w2);
    const float* w_mean = fw ? mp_w[2] : mp_w[3];
    const float* w_max  = fw ? mp_w[4] : mp_w[5];
    int off = fw ? 0 : 60;
    long bc = fw ? (long)(Sz - 1) * Hz : 0;   // broadcast row: hT position

    k_att<<<Bz * 64, 256, 0, stream>>>(PV, HV, ATT);
    k_feats<<<2 * Bz * Sz, 128, 0, stream>>>(ATT, PV, HV, Fmh, Fmp, Fxh, Fxp);
    Match6 m{};
    m.d[0] = {PV, HV + bc, 0, w_full, mvp, off + 0};
    m.d[1] = {PV, Fmh, Hz, w_mean, mvp, off + 20};
    m.d[2] = {PV, Fxh, Hz, w_max, mvp, off + 40};
    m.d[3] = {HV, PV + bc, 0, w_full, mvh, off + 0};
    m.d[4] = {HV, Fmp, Hz, w_mean, mvh, off + 20};
    m.d[5] = {HV, Fxp, Hz, w_max, mvh, off + 40};
    k_match<<<6 * 160, 256, 0, stream>>>(m);
  }

  // ---- agg projections (fp32 src, K=120) + agg LSTMs ----
  {
    Proj8 pa{};
    for (int c = 0; c < 8; ++c) {
      pa.c[c].ids = nullptr; pa.c[c].emb = nullptr;
      pa.c[c].src = MV + (c >> 1) * MV_CH;
      pa.c[c].W = (c & 1) ? agg_Wih_b : agg_Wih_f;
      pa.c[c].bias = (c & 1) ? agg_b_b : agg_b_f;
      pa.c[c].out = XIN + c * XIN_CH;
      pa.c[c].rev = c & 1;
    }
    k_proj<<<8 * Sz * NBK, 256, 0, stream>>>(pa, 120, 4);
  }
  {
    Lstm8 la{};
    for (int c = 0; c < 8; ++c) {
      la.c[c].xin = XIN + c * XIN_CH;
      la.c[c].Whh = (c & 1) ? agg_Whh_b : agg_Whh_f;
      la.c[c].hout = HOUT_B + c * HOUT_CH;
      la.c[c].rev = c & 1;
      la.c[c].store_all = 0;
    }
    k_lstm<<<8, 1024, 0, stream>>>(la);
  }

  // ---- head ----
  k_highway<<<2 * Bz, 512, 0, stream>>>(HOUT_B, hw_lin_w, hw_lin_b, hw_gate_w, hw_gate_b, HW);
  k_fc1<<<Bz, 256, 0, stream>>>(HW, fc1_w, fc1_b, FC1O);
  k_fc2<<<1, 64, 0, stream>>>(FC1O, fc2_w, fc2_b, (float*)d_out);
}

// Round 4
// 1373.940 us; speedup vs baseline: 2.4100x; 1.0019x over previous
//
#include <hip/hip_runtime.h>

// BiMPM on MI355X. Round 4: launch count 23 -> 8 (fused projections, batched
// branch kernels, fused head); k_lstm defers the per-step global h store into
// the next step's MFMA window so barriers no longer drain vmcnt on store-acks.

#define Bz 16
#define Sz 128
#define Hz 100
#define Gz 400      // 4H
#define NT 25       // Gz/16 n-tiles
#define NBK 7       // ceil(25/4) n-tile blocks per t
#define EPSV 1e-8f

#define XIN_CH  ((long)Sz * Bz * Gz)    // 819200
#define HOUT_CH ((long)Bz * Sz * Hz)    // 204800
#define MV_CH   ((long)Bz * Sz * 120)   // 245760
#define BSS     ((long)Bz * Sz * Sz)    // 262144

typedef __attribute__((ext_vector_type(4))) float floatx4;
typedef __attribute__((ext_vector_type(8))) __bf16 bf16x8;

union FragU { bf16x8 v; unsigned u[4]; unsigned short s[8]; };

__device__ __forceinline__ float bf2f(unsigned short h) {
  unsigned u = ((unsigned)h) << 16;
  return __builtin_bit_cast(float, u);
}
__device__ __forceinline__ unsigned short f2bf(float x) {
  unsigned u = __builtin_bit_cast(unsigned, x);
  u = u + 0x7FFFu + ((u >> 16) & 1u);   // RNE
  return (unsigned short)(u >> 16);
}
__device__ __forceinline__ float sigf(float x) { return 1.0f / (1.0f + __expf(-x)); }
__device__ __forceinline__ float tanh_fast(float x) { return 1.0f - 2.0f / (__expf(2.0f * x) + 1.0f); }

#define MFMA(a, b, c) __builtin_amdgcn_mfma_f32_16x16x32_bf16((a), (b), (c), 0, 0, 0)

// chain index helpers for branch groups (grp: 0 word-fw, 1 word-bw, 2 char-fw, 3 char-bw)
__device__ __forceinline__ int pv_chain(int grp) { return (grp < 2 ? 0 : 4) + (grp & 1); }

// ---------------- projection GEMM -------------------------------------------
struct ProjChain {
  const int* ids;       // non-null -> gather rows from emb
  const float* emb;     // V x K fp32
  const float* src;     // B x S x K fp32 (if ids == nullptr)
  const float* W;       // G x K fp32 (row-major)
  const float* bias;    // G fp32
  float* out;           // S x B x G fp32 (time-major)
  int rev;
  int K;
  int ksteps;
};
struct Proj8 { ProjChain c[8]; };

__global__ __launch_bounds__(256) void k_proj(Proj8 P) {
  int bx = blockIdx.x;
  int c = bx / (Sz * NBK);
  int rem = bx % (Sz * NBK);
  int t = rem / NBK;
  int nb = rem % NBK;
  int wave = threadIdx.x >> 6;
  int ntile = nb * 4 + wave;
  if (ntile >= NT) return;
  int lane = threadIdx.x & 63;
  int ml = lane & 15;
  int qd = lane >> 4;

  const ProjChain ch = P.c[c];
  const int K = ch.K;
  int tp = ch.rev ? (Sz - 1 - t) : t;

  const float* arow = ch.ids ? (ch.emb + (long)ch.ids[ml * Sz + tp] * K)
                             : (ch.src + ((long)ml * Sz + tp) * K);
  const float* wrow = ch.W + (long)(ntile * 16 + ml) * K;

  floatx4 acc = {0.f, 0.f, 0.f, 0.f};
  for (int ks = 0; ks < ch.ksteps; ++ks) {
    int k0 = ks * 32 + qd * 8;
    FragU ahi, alo, whi;
#pragma unroll
    for (int j = 0; j < 8; ++j) {
      int k = k0 + j;
      float xv = (k < K) ? arow[k] : 0.f;
      float wv = (k < K) ? wrow[k] : 0.f;
      unsigned short xh = f2bf(xv);
      ahi.s[j] = xh; alo.s[j] = f2bf(xv - bf2f(xh));
      whi.s[j] = f2bf(wv);
    }
    acc = MFMA(ahi.v, whi.v, acc);
    acc = MFMA(alo.v, whi.v, acc);
  }
  int g = ntile * 16 + ml;
  float bv = ch.bias[g];
  float* outp = ch.out + (long)t * Bz * Gz + g;
#pragma unroll
  for (int r = 0; r < 4; ++r) {
    int brow = qd * 4 + r;
    outp[brow * Gz] = acc[r] + bv;
  }
}

// ---------------- LSTM scan: one workgroup per chain --------------------------
struct LstmChain {
  const float* xin;     // S x B x G  (time-major)
  const float* Whh;     // G x H fp32
  float* hout;          // B x S x H fp32 (rev chains stored re-reversed)
  int rev;
  int store_all;        // 1: store h every step; 0: only final h
};
struct Lstm8 { LstmChain c[8]; };

#define ZS 404    // z row stride (floats)
#define HSTR 136  // h row stride in bf16 elems (272B, 16B multiple)

__global__ __launch_bounds__(1024) void k_lstm(Lstm8 P) {
  __shared__ float z[Bz * ZS];
  __shared__ float cst[Bz * Hz];
  __shared__ __align__(16) unsigned short hhi[Bz * HSTR];
  __shared__ __align__(16) unsigned short hlo[Bz * HSTR];

  const LstmChain ch = P.c[blockIdx.x];
  const int tid = threadIdx.x;
  const int wid = tid >> 6;
  const int lane = tid & 63;
  const int nl = lane & 15;
  const int qd = lane >> 4;

  // pointwise-phase constants (item0 = tid, item1 = tid + 1024)
  const int item1 = tid + 1024;
  const bool act0 = tid < Bz * Hz;          // always true (tid<1024<1600)
  const bool act1 = item1 < Bz * Hz;        // first 576 threads
  const int b0 = tid / Hz, j0 = tid % Hz;
  const int b1 = item1 / Hz, j1 = item1 % Hz;

  for (int i = tid; i < Bz * Hz; i += 1024) cst[i] = 0.f;
  for (int i = tid; i < Bz * HSTR; i += 1024) { hhi[i] = 0; hlo[i] = 0; }
  __syncthreads();

  const bool has2 = (wid + 16) < NT;
  const int g0 = wid * 16 + nl;
  const int g1 = (wid + 16) * 16 + nl;

  FragU w0[4], w1[4];
  {
    const float* wr0 = ch.Whh + (long)g0 * Hz;
    const float* wr1 = ch.Whh + (long)g1 * Hz;
#pragma unroll
    for (int ks = 0; ks < 4; ++ks) {
#pragma unroll
      for (int j = 0; j < 8; ++j) {
        int k = ks * 32 + qd * 8 + j;
        w0[ks].s[j] = f2bf((k < Hz) ? wr0[k] : 0.f);
        w1[ks].s[j] = f2bf((has2 && k < Hz) ? wr1[k] : 0.f);
      }
    }
  }

  floatx4 xc0, xc1, xn0, xn1;
#pragma unroll
  for (int r = 0; r < 4; ++r) {
    xc0[r] = ch.xin[(qd * 4 + r) * Gz + g0];
    xc1[r] = has2 ? ch.xin[(qd * 4 + r) * Gz + g1] : 0.f;
  }

  float h0v = 0.f, h1v = 0.f;
  int sprev = 0;

  for (int t = 0; t < Sz; ++t) {
    // deferred global store of step t-1's h (drains during the MFMA window)
    if (ch.store_all && t > 0) {
      ch.hout[((long)b0 * Sz + sprev) * Hz + j0] = h0v;
      if (act1) ch.hout[((long)b1 * Sz + sprev) * Hz + j1] = h1v;
    }
    if (t + 1 < Sz) {
      const float* xp = ch.xin + (long)(t + 1) * Bz * Gz;
#pragma unroll
      for (int r = 0; r < 4; ++r) {
        xn0[r] = xp[(qd * 4 + r) * Gz + g0];
        xn1[r] = has2 ? xp[(qd * 4 + r) * Gz + g1] : 0.f;
      }
    }
    floatx4 acc0 = xc0, acc1 = xc1;
#pragma unroll
    for (int ks = 0; ks < 4; ++ks) {
      FragU ah, al;
      ah.v = *(const bf16x8*)(&hhi[nl * HSTR + ks * 32 + qd * 8]);
      al.v = *(const bf16x8*)(&hlo[nl * HSTR + ks * 32 + qd * 8]);
      acc0 = MFMA(ah.v, w0[ks].v, acc0);
      acc0 = MFMA(al.v, w0[ks].v, acc0);
      if (has2) {
        acc1 = MFMA(ah.v, w1[ks].v, acc1);
        acc1 = MFMA(al.v, w1[ks].v, acc1);
      }
    }
#pragma unroll
    for (int r = 0; r < 4; ++r) {
      z[(qd * 4 + r) * ZS + g0] = acc0[r];
      if (has2) z[(qd * 4 + r) * ZS + g1] = acc1[r];
    }
    __syncthreads();

    int s_store = ch.rev ? (Sz - 1 - t) : t;
    {
      float zi = z[b0 * ZS + j0];
      float zf = z[b0 * ZS + Hz + j0];
      float zg = z[b0 * ZS + 2 * Hz + j0];
      float zo = z[b0 * ZS + 3 * Hz + j0];
      float cold = cst[tid];
      float cnew = sigf(zf) * cold + sigf(zi) * tanh_fast(zg);
      float h = sigf(zo) * tanh_fast(cnew);
      cst[tid] = cnew;
      unsigned short hh = f2bf(h);
      hhi[b0 * HSTR + j0] = hh;
      hlo[b0 * HSTR + j0] = f2bf(h - bf2f(hh));
      h0v = h;
    }
    if (act1) {
      float zi = z[b1 * ZS + j1];
      float zf = z[b1 * ZS + Hz + j1];
      float zg = z[b1 * ZS + 2 * Hz + j1];
      float zo = z[b1 * ZS + 3 * Hz + j1];
      float cold = cst[item1];
      float cnew = sigf(zf) * cold + sigf(zi) * tanh_fast(zg);
      float h = sigf(zo) * tanh_fast(cnew);
      cst[item1] = cnew;
      unsigned short hh = f2bf(h);
      hhi[b1 * HSTR + j1] = hh;
      hlo[b1 * HSTR + j1] = f2bf(h - bf2f(hh));
      h1v = h;
    }
    sprev = s_store;
    __syncthreads();
    xc0 = xn0; xc1 = xn1;
  }
  // final step's h (needed by all chains)
  ch.hout[((long)b0 * Sz + sprev) * Hz + j0] = h0v;
  if (act1) ch.hout[((long)b1 * Sz + sprev) * Hz + j1] = h1v;
}

// ---------------- cosine attention, 4 groups batched --------------------------
__global__ __launch_bounds__(256) void k_att4(const float* houtA, float* att4) {
  int bx = blockIdx.x;
  int grp = bx >> 10;           // 1024 blocks per group
  int rem = bx & 1023;
  int b = rem >> 6;
  int pt = (rem >> 3) & 7;
  int qt = rem & 7;
  int pc = pv_chain(grp);
  const float* pv = houtA + (long)pc * HOUT_CH;
  const float* hv = houtA + (long)(pc + 2) * HOUT_CH;
  float* att = att4 + (long)grp * BSS;

  __shared__ float ps[16 * Hz];
  __shared__ float hs[16 * Hz];
  int tid = threadIdx.x;
  for (int i = tid; i < 16 * Hz; i += 256) {
    int r = i / Hz, h = i % Hz;
    ps[i] = pv[((long)b * Sz + pt * 16 + r) * Hz + h];
    hs[i] = hv[((long)b * Sz + qt * 16 + r) * Hz + h];
  }
  __syncthreads();
  int p = tid >> 4, q = tid & 15;
  const float* pr = &ps[p * Hz];
  const float* hr = &hs[q * Hz];
  float pq = 0.f, pp = 0.f, qq = 0.f;
#pragma unroll 4
  for (int h = 0; h < Hz; ++h) {
    float a = pr[h], bb = hr[h];
    pq += a * bb; pp += a * a; qq += bb * bb;
  }
  float denom = fmaxf(sqrtf(pp) * sqrtf(qq), EPSV);
  att[((long)b * Sz + pt * 16 + p) * Sz + qt * 16 + q] = pq / denom;
}

// ---------------- attention features, 4 groups batched ------------------------
__global__ __launch_bounds__(128) void k_feats4(const float* att4, const float* houtA,
                                                float* feat4) {
  int bx = blockIdx.x;
  int grp = bx / (2 * Bz * Sz);
  int rem = bx % (2 * Bz * Sz);
  int mode = rem / (Bz * Sz);   // 0: rows (h-side), 1: cols (p-side)
  int rem2 = rem % (Bz * Sz);
  int b = rem2 / Sz;
  int r = rem2 % Sz;
  int pc = pv_chain(grp);
  const float* pv = houtA + (long)pc * HOUT_CH;
  const float* hv = houtA + (long)(pc + 2) * HOUT_CH;
  const float* att = att4 + (long)grp * BSS;
  float* fb = feat4 + (long)grp * 4 * HOUT_CH;
  float* mean_h = fb;
  float* mean_p = fb + HOUT_CH;
  float* max_h  = fb + 2 * HOUT_CH;
  float* max_p  = fb + 3 * HOUT_CH;

  __shared__ float arow[Sz];
  int tid = threadIdx.x;
  if (mode == 0) arow[tid] = att[((long)b * Sz + r) * Sz + tid];
  else           arow[tid] = att[((long)b * Sz + tid) * Sz + r];
  __syncthreads();
  float asum = 0.f;
  for (int k = 0; k < Sz; ++k) asum += arow[k];
  const float* src = (mode == 0) ? hv : pv;
  if (tid < Hz) {
    float acc = 0.f, mx = -1e30f;
    for (int k = 0; k < Sz; ++k) {
      float a = arow[k];
      float v = src[((long)b * Sz + k) * Hz + tid];
      float pr = a * v;
      acc += pr;
      mx = fmaxf(mx, pr);
    }
    float mean = acc / fmaxf(asum, EPSV);
    long o = ((long)b * Sz + r) * Hz + tid;
    if (mode == 0) { mean_h[o] = mean; max_h[o] = mx; }
    else           { mean_p[o] = mean; max_p[o] = mx; }
  }
}

// ---------------- multi-perspective match, 24 instances batched ---------------
struct MatchArgs {
  const float* houtA;
  const float* feat4;
  float* mv;
  const float* w_full[4];   // per-group full-match weight
  const float* w3; const float* w4; const float* w5; const float* w6;
};

__global__ __launch_bounds__(256) void k_match24(MatchArgs M) {
  int bx = blockIdx.x;
  int grp = bx / (6 * 160);
  int rem = bx % (6 * 160);
  int inst = rem / 160;
  int idx = (rem % 160) * 256 + threadIdx.x;   // B*S*L = 40960
  int l = idx % 20;
  int s = (idx / 20) % Sz;
  int b = idx / (20 * Sz);

  int fw = !(grp & 1);
  int word = grp < 2;
  int pc = pv_chain(grp);
  const float* PV = M.houtA + (long)pc * HOUT_CH;
  const float* HV = M.houtA + (long)(pc + 2) * HOUT_CH;
  const float* fb = M.feat4 + (long)grp * 4 * HOUT_CH;
  float* mvp = M.mv + (word ? 0 : 2) * MV_CH;
  float* mvh = mvp + MV_CH;
  long bc = fw ? (long)(Sz - 1) * Hz : 0;
  int off = fw ? 0 : 60;

  const float* v1; const float* v2; int v2s; const float* w; float* outb; int oo;
  switch (inst) {
    case 0: v1 = PV; v2 = HV + bc;          v2s = 0;  w = M.w_full[grp];      outb = mvp; oo = off;      break;
    case 1: v1 = PV; v2 = fb;               v2s = Hz; w = fw ? M.w3 : M.w4;   outb = mvp; oo = off + 20; break;
    case 2: v1 = PV; v2 = fb + 2 * HOUT_CH; v2s = Hz; w = fw ? M.w5 : M.w6;   outb = mvp; oo = off + 40; break;
    case 3: v1 = HV; v2 = PV + bc;          v2s = 0;  w = M.w_full[grp];      outb = mvh; oo = off;      break;
    case 4: v1 = HV; v2 = fb + HOUT_CH;     v2s = Hz; w = fw ? M.w3 : M.w4;   outb = mvh; oo = off + 20; break;
    default: v1 = HV; v2 = fb + 3 * HOUT_CH; v2s = Hz; w = fw ? M.w5 : M.w6;  outb = mvh; oo = off + 40; break;
  }
  const float* p1 = v1 + ((long)b * Sz + s) * Hz;
  const float* p2 = v2 + (long)b * Sz * Hz + (long)s * v2s;
  const float* wr = w + l * Hz;
  float num = 0.f, n1 = 0.f, n2 = 0.f;
#pragma unroll 4
  for (int h = 0; h < Hz; ++h) {
    float ww = wr[h];
    float wsq = ww * ww;
    float a = p1[h], c = p2[h];
    num += a * c * wsq;
    n1  += a * a * wsq;
    n2  += c * c * wsq;
  }
  float denom = fmaxf(sqrtf(n1) * sqrtf(n2), EPSV);
  outb[((long)b * Sz + s) * 120 + oo + l] = num / denom;
}

// ---------------- fused head: highway + fc1 + fc2, one block per b ------------
__global__ __launch_bounds__(1024) void k_head(const float* houtB,
                                               const float* lw, const float* lb,
                                               const float* gw, const float* gb,
                                               const float* f1w, const float* f1b,
                                               const float* f2w, const float* f2b,
                                               float* out) {
  int b = blockIdx.x;
  __shared__ float xr[800];
  __shared__ float hwv[800];
  __shared__ float f1[200];
  int tid = threadIdx.x;
  if (tid < 800) {
    int seq = tid / Gz;           // 0: wx, 1: cx
    int i = tid % Gz;
    int seg = i / Hz, j = i % Hz;
    int chain = seq * 4 + seg;
    int s_sel = (seg & 1) ? 0 : (Sz - 1);
    xr[tid] = houtB[((long)chain * Bz + b) * Sz * Hz + (long)s_sel * Hz + j];
  }
  __syncthreads();
  if (tid < 800) {
    int seq = tid / Gz;
    int o = tid % Gz;
    const float* xs = xr + seq * Gz;
    const float* lwr = lw + (long)o * Gz;
    const float* gwr = gw + (long)o * Gz;
    float al = 0.f, ag = 0.f;
#pragma unroll 4
    for (int k = 0; k < Gz; ++k) {
      float x = xs[k];
      al += x * lwr[k];
      ag += x * gwr[k];
    }
    al += lb[o];
    ag += gb[o];
    float hlin = fmaxf(al, 0.f);
    float tg = sigf(ag);
    hwv[tid] = tg * hlin + (1.f - tg) * xs[o];
  }
  __syncthreads();
  if (tid < 200) {
    const float* wr = f1w + (long)tid * 800;
    float acc = f1b[tid];
#pragma unroll 4
    for (int k = 0; k < 800; ++k) acc += hwv[k] * wr[k];
    f1[tid] = tanh_fast(acc);
  }
  __syncthreads();
  if (tid < 3) {
    const float* wr = f2w + tid * 200;
    float acc = f2b[tid];
    for (int k = 0; k < 200; ++k) acc += f1[k] * wr[k];
    out[b * 3 + tid] = acc;
  }
}

// ---------------- host orchestration -----------------------------------------
extern "C" void kernel_launch(void* const* d_in, const int* in_sizes, int n_in,
                              void* d_out, int out_size, void* d_ws, size_t ws_size,
                              hipStream_t stream) {
  (void)in_sizes; (void)n_in; (void)out_size;

  const int* p_ids  = (const int*)d_in[0];
  const int* h_ids  = (const int*)d_in[1];
  const int* cp_ids = (const int*)d_in[2];
  const int* ch_ids = (const int*)d_in[3];
  const float* word_emb = (const float*)d_in[4];
  const float* char_emb = (const float*)d_in[5];
  const float* ctx_Wih_f = (const float*)d_in[6];
  const float* ctx_Whh_f = (const float*)d_in[7];
  const float* ctx_b_f   = (const float*)d_in[8];
  const float* ctx_Wih_b = (const float*)d_in[9];
  const float* ctx_Whh_b = (const float*)d_in[10];
  const float* ctx_b_b   = (const float*)d_in[11];
  const float* chr_Wih_f = (const float*)d_in[12];
  const float* chr_Whh_f = (const float*)d_in[13];
  const float* chr_b_f   = (const float*)d_in[14];
  const float* chr_Wih_b = (const float*)d_in[15];
  const float* chr_Whh_b = (const float*)d_in[16];
  const float* chr_b_b   = (const float*)d_in[17];
  const float* agg_Wih_f = (const float*)d_in[18];
  const float* agg_Whh_f = (const float*)d_in[19];
  const float* agg_b_f   = (const float*)d_in[20];
  const float* agg_Wih_b = (const float*)d_in[21];
  const float* agg_Whh_b = (const float*)d_in[22];
  const float* agg_b_b   = (const float*)d_in[23];
  const float* mp_w1 = (const float*)d_in[24];
  const float* mp_w2 = (const float*)d_in[25];
  const float* mp_w3 = (const float*)d_in[26];
  const float* mp_w4 = (const float*)d_in[27];
  const float* mp_w5 = (const float*)d_in[28];
  const float* mp_w6 = (const float*)d_in[29];
  const float* char_w1 = (const float*)d_in[30];
  const float* char_w2 = (const float*)d_in[31];
  const float* hw_lin_w  = (const float*)d_in[32];
  const float* hw_lin_b  = (const float*)d_in[33];
  const float* hw_gate_w = (const float*)d_in[34];
  const float* hw_gate_b = (const float*)d_in[35];
  const float* fc1_w = (const float*)d_in[36];
  const float* fc1_b = (const float*)d_in[37];
  const float* fc2_w = (const float*)d_in[38];
  const float* fc2_b = (const float*)d_in[39];

  float* ws = (float*)d_ws;
  float* XIN    = ws;                         // 8 * XIN_CH (reused A -> B)
  float* ATT4   = XIN;                        // alias: dead between lstmA and projB
  float* FEAT4  = XIN + 4 * BSS;              // 4 groups x 4 feats x HOUT_CH
  float* HOUT_A = XIN + 8 * XIN_CH;
  float* HOUT_B = HOUT_A + 8 * HOUT_CH;
  float* MV     = HOUT_B + 8 * HOUT_CH;
  size_t needed = (size_t)((MV + 4 * MV_CH) - ws) * 4;
  if (ws_size < needed) return;

  // ---- 1. fused phase-A projections (word K=300, char K=50) ----
  {
    Proj8 pc{};
    const int* idv[8] = {p_ids, p_ids, h_ids, h_ids, cp_ids, cp_ids, ch_ids, ch_ids};
    for (int c = 0; c < 8; ++c) {
      int word = c < 4;
      pc.c[c].ids = idv[c];
      pc.c[c].emb = word ? word_emb : char_emb;
      pc.c[c].src = nullptr;
      pc.c[c].W    = word ? ((c & 1) ? ctx_Wih_b : ctx_Wih_f) : ((c & 1) ? chr_Wih_b : chr_Wih_f);
      pc.c[c].bias = word ? ((c & 1) ? ctx_b_b : ctx_b_f)     : ((c & 1) ? chr_b_b : chr_b_f);
      pc.c[c].out = XIN + c * XIN_CH;
      pc.c[c].rev = c & 1;
      pc.c[c].K = word ? 300 : 50;
      pc.c[c].ksteps = word ? 10 : 2;
    }
    k_proj<<<8 * Sz * NBK, 256, 0, stream>>>(pc);
  }
  // ---- 2. phase-A LSTMs ----
  {
    Lstm8 la{};
    for (int c = 0; c < 8; ++c) {
      la.c[c].xin = XIN + c * XIN_CH;
      la.c[c].Whh = (c < 4) ? ((c & 1) ? ctx_Whh_b : ctx_Whh_f)
                            : ((c & 1) ? chr_Whh_b : chr_Whh_f);
      la.c[c].hout = HOUT_A + c * HOUT_CH;
      la.c[c].rev = c & 1;
      la.c[c].store_all = 1;
    }
    k_lstm<<<8, 1024, 0, stream>>>(la);
  }
  // ---- 3-5. branch, all 4 groups batched ----
  k_att4<<<4 * Bz * 64, 256, 0, stream>>>(HOUT_A, ATT4);
  k_feats4<<<4 * 2 * Bz * Sz, 128, 0, stream>>>(ATT4, HOUT_A, FEAT4);
  {
    MatchArgs m{};
    m.houtA = HOUT_A; m.feat4 = FEAT4; m.mv = MV;
    m.w_full[0] = mp_w1; m.w_full[1] = mp_w2; m.w_full[2] = char_w1; m.w_full[3] = char_w2;
    m.w3 = mp_w3; m.w4 = mp_w4; m.w5 = mp_w5; m.w6 = mp_w6;
    k_match24<<<4 * 6 * 160, 256, 0, stream>>>(m);
  }
  // ---- 6. phase-B projections (K=120) ----
  {
    Proj8 pa{};
    for (int c = 0; c < 8; ++c) {
      pa.c[c].ids = nullptr; pa.c[c].emb = nullptr;
      pa.c[c].src = MV + (c >> 1) * MV_CH;
      pa.c[c].W = (c & 1) ? agg_Wih_b : agg_Wih_f;
      pa.c[c].bias = (c & 1) ? agg_b_b : agg_b_f;
      pa.c[c].out = XIN + c * XIN_CH;
      pa.c[c].rev = c & 1;
      pa.c[c].K = 120;
      pa.c[c].ksteps = 4;
    }
    k_proj<<<8 * Sz * NBK, 256, 0, stream>>>(pa);
  }
  // ---- 7. phase-B LSTMs (final h only) ----
  {
    Lstm8 la{};
    for (int c = 0; c < 8; ++c) {
      la.c[c].xin = XIN + c * XIN_CH;
      la.c[c].Whh = (c & 1) ? agg_Whh_b : agg_Whh_f;
      la.c[c].hout = HOUT_B + c * HOUT_CH;
      la.c[c].rev = c & 1;
      la.c[c].store_all = 0;
    }
    k_lstm<<<8, 1024, 0, stream>>>(la);
  }
  // ---- 8. fused head ----
  k_head<<<Bz, 1024, 0, stream>>>(HOUT_B, hw_lin_w, hw_lin_b, hw_gate_w, hw_gate_b,
                                  fc1_w, fc1_b, fc2_w, fc2_b, (float*)d_out);
}

// Round 5
// 1194.313 us; speedup vs baseline: 2.7725x; 1.1504x over previous
//
#include <hip/hip_runtime.h>

// BiMPM on MI355X. Round 5: single-barrier LSTM. Gate-interleaved weight rows
// (p = hidden*4+gate) let each wave redistribute z to pointwise lanes through a
// wave-private LDS slice (no barrier needed: in-order LDS pipe within a wave).
// c persists in registers; h double-buffered (parity) in LDS as bf16 hi/lo;
// coalesced deferred global h stores via an fp32 LDS stage. xin is [t][p][b]
// so x loads are float4. One __syncthreads per step.

#define Bz 16
#define Sz 128
#define Hz 100
#define Gz 400      // 4H
#define NT 25       // Gz/16 n-tiles
#define NBK 7       // ceil(25/4) n-tile blocks per t
#define EPSV 1e-8f

#define XIN_CH  ((long)Sz * Bz * Gz)    // 819200
#define HOUT_CH ((long)Bz * Sz * Hz)    // 204800
#define MV_CH   ((long)Bz * Sz * 120)   // 245760
#define BSS     ((long)Bz * Sz * Sz)    // 262144

typedef __attribute__((ext_vector_type(4))) float floatx4;
typedef __attribute__((ext_vector_type(8))) __bf16 bf16x8;

union FragU { bf16x8 v; unsigned u[4]; unsigned short s[8]; };

__device__ __forceinline__ float bf2f(unsigned short h) {
  unsigned u = ((unsigned)h) << 16;
  return __builtin_bit_cast(float, u);
}
__device__ __forceinline__ unsigned short f2bf(float x) {
  unsigned u = __builtin_bit_cast(unsigned, x);
  u = u + 0x7FFFu + ((u >> 16) & 1u);   // RNE
  return (unsigned short)(u >> 16);
}
__device__ __forceinline__ float sigf(float x) { return 1.0f / (1.0f + __expf(-x)); }
__device__ __forceinline__ float tanh_fast(float x) { return 1.0f - 2.0f / (__expf(2.0f * x) + 1.0f); }

#define MFMA(a, b, c) __builtin_amdgcn_mfma_f32_16x16x32_bf16((a), (b), (c), 0, 0, 0)

__device__ __forceinline__ int pv_chain(int grp) { return (grp < 2 ? 0 : 4) + (grp & 1); }

// ---------------- projection GEMM (gate-interleaved output rows) -------------
// out[t][p][b], p = hidden*4+gate; W/bias rows fetched at orig = gate*Hz+hidden.
struct ProjChain {
  const int* ids;
  const float* emb;
  const float* src;
  const float* W;       // G x K fp32 (original row order)
  const float* bias;    // G fp32 (original order)
  float* out;           // S x G x B fp32, gate-interleaved p
  int rev;
  int K;
  int ksteps;
};
struct Proj8 { ProjChain c[8]; };

__global__ __launch_bounds__(256) void k_proj(Proj8 P) {
  int bx = blockIdx.x;
  int c = bx / (Sz * NBK);
  int rem = bx % (Sz * NBK);
  int t = rem / NBK;
  int nb = rem % NBK;
  int wave = threadIdx.x >> 6;
  int ntile = nb * 4 + wave;
  if (ntile >= NT) return;
  int lane = threadIdx.x & 63;
  int ml = lane & 15;
  int qd = lane >> 4;

  const ProjChain ch = P.c[c];
  const int K = ch.K;
  int tp = ch.rev ? (Sz - 1 - t) : t;

  const float* arow = ch.ids ? (ch.emb + (long)ch.ids[ml * Sz + tp] * K)
                             : (ch.src + ((long)ml * Sz + tp) * K);
  int p = ntile * 16 + ml;
  int orig_row = (ml & 3) * Hz + (ntile * 4) + (ml >> 2);
  const float* wrow = ch.W + (long)orig_row * K;

  floatx4 acc = {0.f, 0.f, 0.f, 0.f};
  for (int ks = 0; ks < ch.ksteps; ++ks) {
    int k0 = ks * 32 + qd * 8;
    FragU ahi, alo, whi;
#pragma unroll
    for (int j = 0; j < 8; ++j) {
      int k = k0 + j;
      float xv = (k < K) ? arow[k] : 0.f;
      float wv = (k < K) ? wrow[k] : 0.f;
      unsigned short xh = f2bf(xv);
      ahi.s[j] = xh; alo.s[j] = f2bf(xv - bf2f(xh));
      whi.s[j] = f2bf(wv);
    }
    acc = MFMA(ahi.v, whi.v, acc);
    acc = MFMA(alo.v, whi.v, acc);
  }
  float bv = ch.bias[orig_row];
#pragma unroll
  for (int r = 0; r < 4; ++r) acc[r] += bv;
  // store float4: out[t][p][qd*4 .. qd*4+3]
  *(floatx4*)(ch.out + (long)t * Bz * Gz + (long)p * Bz + qd * 4) = acc;
}

// ---------------- LSTM scan: one workgroup per chain, 1 barrier/step ----------
struct LstmChain {
  const float* xin;     // S x G x B (gate-interleaved p, batch-minor)
  const float* Whh;     // G x H fp32 (original row order)
  float* hout;          // B x S x H fp32
  int rev;
  int store_all;
};
struct Lstm8 { LstmChain c[8]; };

#define HSTR 144   // h row stride in bf16 elems (288B: 16B-aligned, bank-spread)
#define ZXS 20     // zx row stride (floats): 4-word aligned rows

__global__ __launch_bounds__(1024) void k_lstm(Lstm8 P) {
  __shared__ float zx[16 * 16 * ZXS];                       // per-wave 16x20
  __shared__ float hfp[2][Bz * Hz];                         // fp32 h stage
  __shared__ __align__(16) unsigned short hhi[2][Bz * HSTR];
  __shared__ __align__(16) unsigned short hlo[2][Bz * HSTR];

  const LstmChain ch = P.c[blockIdx.x];
  const int tid = threadIdx.x;
  const int wid = tid >> 6;
  const int lane = tid & 63;
  const int nl = lane & 15;
  const int qd = lane >> 4;
  const int g  = nl & 3;          // my item's gate-slot -> batch low bits
  const int hl = nl >> 2;         // my item's hidden_local
  const int bi = qd * 4 + g;      // my item's batch

  for (int i = tid; i < 2 * Bz * HSTR; i += 1024) {
    ((unsigned short*)hhi)[i] = 0; ((unsigned short*)hlo)[i] = 0;
  }
  __syncthreads();

  const bool has2 = wid < 9;
  const int nt0 = wid, nt1 = wid + 16;

  // Whh B-frags (bf16-hi), permuted rows
  FragU w0[4], w1[4];
  {
    int orig0 = (nl & 3) * Hz + nt0 * 4 + (nl >> 2);
    int orig1 = (nl & 3) * Hz + nt1 * 4 + (nl >> 2);
    const float* wr0 = ch.Whh + (long)orig0 * Hz;
    const float* wr1 = ch.Whh + (long)orig1 * Hz;
#pragma unroll
    for (int ks = 0; ks < 4; ++ks) {
#pragma unroll
      for (int j = 0; j < 8; ++j) {
        int k = ks * 32 + qd * 8 + j;
        w0[ks].s[j] = f2bf((k < Hz) ? wr0[k] : 0.f);
        w1[ks].s[j] = f2bf((has2 && k < Hz) ? wr1[k] : 0.f);
      }
    }
  }

  // x prefetch t=0 (float4: xin[t][p][qd*4..+3])
  floatx4 xc0 = *(const floatx4*)(ch.xin + (long)(nt0 * 16 + nl) * Bz + qd * 4);
  floatx4 xc1 = has2 ? *(const floatx4*)(ch.xin + (long)(nt1 * 16 + nl) * Bz + qd * 4)
                     : floatx4{0.f, 0.f, 0.f, 0.f};

  float c0 = 0.f, c1 = 0.f;
  float* zme = &zx[wid * 16 * ZXS];
  const int item1 = tid + 1024;                  // hfp->global item indices
  const int sb0 = tid / Hz,  sj0 = tid % Hz;
  const int sb1 = item1 / Hz, sj1 = item1 % Hz;
  const bool act1 = item1 < Bz * Hz;

  for (int t = 0; t < Sz; ++t) {
    // deferred coalesced store of h(t-1)
    if (ch.store_all && t > 0) {
      int pb = (t - 1) & 1;
      int sprev = ch.rev ? (Sz - t) : (t - 1);
      ch.hout[((long)sb0 * Sz + sprev) * Hz + sj0] = hfp[pb][tid];
      if (act1) ch.hout[((long)sb1 * Sz + sprev) * Hz + sj1] = hfp[pb][item1];
    }
    floatx4 xn0 = xc0, xn1 = xc1;
    if (t + 1 < Sz) {
      const float* xp = ch.xin + (long)(t + 1) * Bz * Gz;
      xn0 = *(const floatx4*)(xp + (long)(nt0 * 16 + nl) * Bz + qd * 4);
      if (has2) xn1 = *(const floatx4*)(xp + (long)(nt1 * 16 + nl) * Bz + qd * 4);
    }
    const int rp = t & 1;         // h parity to read
    floatx4 a0 = xc0, a1 = xc1;
#pragma unroll
    for (int ks = 0; ks < 4; ++ks) {
      FragU ah, al;
      ah.v = *(const bf16x8*)(&hhi[rp][nl * HSTR + ks * 32 + qd * 8]);
      al.v = *(const bf16x8*)(&hlo[rp][nl * HSTR + ks * 32 + qd * 8]);
      a0 = MFMA(ah.v, w0[ks].v, a0);
      a0 = MFMA(al.v, w0[ks].v, a0);
      if (has2) {
        a1 = MFMA(ah.v, w1[ks].v, a1);
        a1 = MFMA(al.v, w1[ks].v, a1);
      }
    }
    const int wp = rp ^ 1;        // h parity to write
    // ---- tile0: in-wave z exchange + pointwise ----
#pragma unroll
    for (int r = 0; r < 4; ++r) zme[(qd * 4 + r) * ZXS + nl] = a0[r];
    {
      floatx4 z4 = *(const floatx4*)(&zme[bi * ZXS + hl * 4]);   // i,f,g,o
      float cn = sigf(z4[1]) * c0 + sigf(z4[0]) * tanh_fast(z4[2]);
      float h = sigf(z4[3]) * tanh_fast(cn);
      c0 = cn;
      int hid = nt0 * 4 + hl;
      unsigned short hh = f2bf(h);
      hhi[wp][bi * HSTR + hid] = hh;
      hlo[wp][bi * HSTR + hid] = f2bf(h - bf2f(hh));
      hfp[t & 1][bi * Hz + hid] = h;
    }
    if (has2) {
#pragma unroll
      for (int r = 0; r < 4; ++r) zme[(qd * 4 + r) * ZXS + nl] = a1[r];
      floatx4 z4 = *(const floatx4*)(&zme[bi * ZXS + hl * 4]);
      float cn = sigf(z4[1]) * c1 + sigf(z4[0]) * tanh_fast(z4[2]);
      float h = sigf(z4[3]) * tanh_fast(cn);
      c1 = cn;
      int hid = nt1 * 4 + hl;
      unsigned short hh = f2bf(h);
      hhi[wp][bi * HSTR + hid] = hh;
      hlo[wp][bi * HSTR + hid] = f2bf(h - bf2f(hh));
      hfp[t & 1][bi * Hz + hid] = h;
    }
    __syncthreads();
    xc0 = xn0; xc1 = xn1;
  }
  // final h store (all chains need hT)
  {
    int pb = (Sz - 1) & 1;
    int slast = ch.rev ? 0 : (Sz - 1);
    ch.hout[((long)sb0 * Sz + slast) * Hz + sj0] = hfp[pb][tid];
    if (act1) ch.hout[((long)sb1 * Sz + slast) * Hz + sj1] = hfp[pb][item1];
  }
}

// ---------------- cosine attention, 4 groups batched --------------------------
__global__ __launch_bounds__(256) void k_att4(const float* houtA, float* att4) {
  int bx = blockIdx.x;
  int grp = bx >> 10;
  int rem = bx & 1023;
  int b = rem >> 6;
  int pt = (rem >> 3) & 7;
  int qt = rem & 7;
  int pc = pv_chain(grp);
  const float* pv = houtA + (long)pc * HOUT_CH;
  const float* hv = houtA + (long)(pc + 2) * HOUT_CH;
  float* att = att4 + (long)grp * BSS;

  __shared__ float ps[16 * Hz];
  __shared__ float hs[16 * Hz];
  int tid = threadIdx.x;
  for (int i = tid; i < 16 * Hz; i += 256) {
    int r = i / Hz, h = i % Hz;
    ps[i] = pv[((long)b * Sz + pt * 16 + r) * Hz + h];
    hs[i] = hv[((long)b * Sz + qt * 16 + r) * Hz + h];
  }
  __syncthreads();
  int p = tid >> 4, q = tid & 15;
  const float* pr = &ps[p * Hz];
  const float* hr = &hs[q * Hz];
  float pq = 0.f, pp = 0.f, qq = 0.f;
#pragma unroll 4
  for (int h = 0; h < Hz; ++h) {
    float a = pr[h], bb = hr[h];
    pq += a * bb; pp += a * a; qq += bb * bb;
  }
  float denom = fmaxf(sqrtf(pp) * sqrtf(qq), EPSV);
  att[((long)b * Sz + pt * 16 + p) * Sz + qt * 16 + q] = pq / denom;
}

// ---------------- attention features, 4 groups batched ------------------------
__global__ __launch_bounds__(128) void k_feats4(const float* att4, const float* houtA,
                                                float* feat4) {
  int bx = blockIdx.x;
  int grp = bx / (2 * Bz * Sz);
  int rem = bx % (2 * Bz * Sz);
  int mode = rem / (Bz * Sz);
  int rem2 = rem % (Bz * Sz);
  int b = rem2 / Sz;
  int r = rem2 % Sz;
  int pc = pv_chain(grp);
  const float* pv = houtA + (long)pc * HOUT_CH;
  const float* hv = houtA + (long)(pc + 2) * HOUT_CH;
  const float* att = att4 + (long)grp * BSS;
  float* fb = feat4 + (long)grp * 4 * HOUT_CH;
  float* mean_h = fb;
  float* mean_p = fb + HOUT_CH;
  float* max_h  = fb + 2 * HOUT_CH;
  float* max_p  = fb + 3 * HOUT_CH;

  __shared__ float arow[Sz];
  int tid = threadIdx.x;
  if (mode == 0) arow[tid] = att[((long)b * Sz + r) * Sz + tid];
  else           arow[tid] = att[((long)b * Sz + tid) * Sz + r];
  __syncthreads();
  float asum = 0.f;
  for (int k = 0; k < Sz; ++k) asum += arow[k];
  const float* src = (mode == 0) ? hv : pv;
  if (tid < Hz) {
    float acc = 0.f, mx = -1e30f;
    for (int k = 0; k < Sz; ++k) {
      float a = arow[k];
      float v = src[((long)b * Sz + k) * Hz + tid];
      float pr = a * v;
      acc += pr;
      mx = fmaxf(mx, pr);
    }
    float mean = acc / fmaxf(asum, EPSV);
    long o = ((long)b * Sz + r) * Hz + tid;
    if (mode == 0) { mean_h[o] = mean; max_h[o] = mx; }
    else           { mean_p[o] = mean; max_p[o] = mx; }
  }
}

// ---------------- multi-perspective match, 24 instances batched ---------------
struct MatchArgs {
  const float* houtA;
  const float* feat4;
  float* mv;
  const float* w_full[4];
  const float* w3; const float* w4; const float* w5; const float* w6;
};

__global__ __launch_bounds__(256) void k_match24(MatchArgs M) {
  int bx = blockIdx.x;
  int grp = bx / (6 * 160);
  int rem = bx % (6 * 160);
  int inst = rem / 160;
  int idx = (rem % 160) * 256 + threadIdx.x;
  int l = idx % 20;
  int s = (idx / 20) % Sz;
  int b = idx / (20 * Sz);

  int fw = !(grp & 1);
  int word = grp < 2;
  int pc = pv_chain(grp);
  const float* PV = M.houtA + (long)pc * HOUT_CH;
  const float* HV = M.houtA + (long)(pc + 2) * HOUT_CH;
  const float* fb = M.feat4 + (long)grp * 4 * HOUT_CH;
  float* mvp = M.mv + (word ? 0 : 2) * MV_CH;
  float* mvh = mvp + MV_CH;
  long bc = fw ? (long)(Sz - 1) * Hz : 0;
  int off = fw ? 0 : 60;

  const float* v1; const float* v2; int v2s; const float* w; float* outb; int oo;
  switch (inst) {
    case 0: v1 = PV; v2 = HV + bc;          v2s = 0;  w = M.w_full[grp];      outb = mvp; oo = off;      break;
    case 1: v1 = PV; v2 = fb;               v2s = Hz; w = fw ? M.w3 : M.w4;   outb = mvp; oo = off + 20; break;
    case 2: v1 = PV; v2 = fb + 2 * HOUT_CH; v2s = Hz; w = fw ? M.w5 : M.w6;   outb = mvp; oo = off + 40; break;
    case 3: v1 = HV; v2 = PV + bc;          v2s = 0;  w = M.w_full[grp];      outb = mvh; oo = off;      break;
    case 4: v1 = HV; v2 = fb + HOUT_CH;     v2s = Hz; w = fw ? M.w3 : M.w4;   outb = mvh; oo = off + 20; break;
    default: v1 = HV; v2 = fb + 3 * HOUT_CH; v2s = Hz; w = fw ? M.w5 : M.w6;  outb = mvh; oo = off + 40; break;
  }
  const float* p1 = v1 + ((long)b * Sz + s) * Hz;
  const float* p2 = v2 + (long)b * Sz * Hz + (long)s * v2s;
  const float* wr = w + l * Hz;
  float num = 0.f, n1 = 0.f, n2 = 0.f;
#pragma unroll 4
  for (int h = 0; h < Hz; ++h) {
    float ww = wr[h];
    float wsq = ww * ww;
    float a = p1[h], c = p2[h];
    num += a * c * wsq;
    n1  += a * a * wsq;
    n2  += c * c * wsq;
  }
  float denom = fmaxf(sqrtf(n1) * sqrtf(n2), EPSV);
  outb[((long)b * Sz + s) * 120 + oo + l] = num / denom;
}

// ---------------- fused head -------------------------------------------------
__global__ __launch_bounds__(1024) void k_head(const float* houtB,
                                               const float* lw, const float* lb,
                                               const float* gw, const float* gb,
                                               const float* f1w, const float* f1b,
                                               const float* f2w, const float* f2b,
                                               float* out) {
  int b = blockIdx.x;
  __shared__ float xr[800];
  __shared__ float hwv[800];
  __shared__ float f1[200];
  int tid = threadIdx.x;
  if (tid < 800) {
    int seq = tid / Gz;
    int i = tid % Gz;
    int seg = i / Hz, j = i % Hz;
    int chain = seq * 4 + seg;
    int s_sel = (seg & 1) ? 0 : (Sz - 1);
    xr[tid] = houtB[((long)chain * Bz + b) * Sz * Hz + (long)s_sel * Hz + j];
  }
  __syncthreads();
  if (tid < 800) {
    int seq = tid / Gz;
    int o = tid % Gz;
    const float* xs = xr + seq * Gz;
    const float* lwr = lw + (long)o * Gz;
    const float* gwr = gw + (long)o * Gz;
    float al = 0.f, ag = 0.f;
#pragma unroll 4
    for (int k = 0; k < Gz; ++k) {
      float x = xs[k];
      al += x * lwr[k];
      ag += x * gwr[k];
    }
    al += lb[o];
    ag += gb[o];
    float hlin = fmaxf(al, 0.f);
    float tg = sigf(ag);
    hwv[tid] = tg * hlin + (1.f - tg) * xs[o];
  }
  __syncthreads();
  if (tid < 200) {
    const float* wr = f1w + (long)tid * 800;
    float acc = f1b[tid];
#pragma unroll 4
    for (int k = 0; k < 800; ++k) acc += hwv[k] * wr[k];
    f1[tid] = tanh_fast(acc);
  }
  __syncthreads();
  if (tid < 3) {
    const float* wr = f2w + tid * 200;
    float acc = f2b[tid];
    for (int k = 0; k < 200; ++k) acc += f1[k] * wr[k];
    out[b * 3 + tid] = acc;
  }
}

// ---------------- host orchestration -----------------------------------------
extern "C" void kernel_launch(void* const* d_in, const int* in_sizes, int n_in,
                              void* d_out, int out_size, void* d_ws, size_t ws_size,
                              hipStream_t stream) {
  (void)in_sizes; (void)n_in; (void)out_size;

  const int* p_ids  = (const int*)d_in[0];
  const int* h_ids  = (const int*)d_in[1];
  const int* cp_ids = (const int*)d_in[2];
  const int* ch_ids = (const int*)d_in[3];
  const float* word_emb = (const float*)d_in[4];
  const float* char_emb = (const float*)d_in[5];
  const float* ctx_Wih_f = (const float*)d_in[6];
  const float* ctx_Whh_f = (const float*)d_in[7];
  const float* ctx_b_f   = (const float*)d_in[8];
  const float* ctx_Wih_b = (const float*)d_in[9];
  const float* ctx_Whh_b = (const float*)d_in[10];
  const float* ctx_b_b   = (const float*)d_in[11];
  const float* chr_Wih_f = (const float*)d_in[12];
  const float* chr_Whh_f = (const float*)d_in[13];
  const float* chr_b_f   = (const float*)d_in[14];
  const float* chr_Wih_b = (const float*)d_in[15];
  const float* chr_Whh_b = (const float*)d_in[16];
  const float* chr_b_b   = (const float*)d_in[17];
  const float* agg_Wih_f = (const float*)d_in[18];
  const float* agg_Whh_f = (const float*)d_in[19];
  const float* agg_b_f   = (const float*)d_in[20];
  const float* agg_Wih_b = (const float*)d_in[21];
  const float* agg_Whh_b = (const float*)d_in[22];
  const float* agg_b_b   = (const float*)d_in[23];
  const float* mp_w1 = (const float*)d_in[24];
  const float* mp_w2 = (const float*)d_in[25];
  const float* mp_w3 = (const float*)d_in[26];
  const float* mp_w4 = (const float*)d_in[27];
  const float* mp_w5 = (const float*)d_in[28];
  const float* mp_w6 = (const float*)d_in[29];
  const float* char_w1 = (const float*)d_in[30];
  const float* char_w2 = (const float*)d_in[31];
  const float* hw_lin_w  = (const float*)d_in[32];
  const float* hw_lin_b  = (const float*)d_in[33];
  const float* hw_gate_w = (const float*)d_in[34];
  const float* hw_gate_b = (const float*)d_in[35];
  const float* fc1_w = (const float*)d_in[36];
  const float* fc1_b = (const float*)d_in[37];
  const float* fc2_w = (const float*)d_in[38];
  const float* fc2_b = (const float*)d_in[39];

  float* ws = (float*)d_ws;
  float* XIN    = ws;                         // 8 * XIN_CH (reused A -> B)
  float* ATT4   = XIN;                        // alias: dead between lstmA and projB
  float* FEAT4  = XIN + 4 * BSS;
  float* HOUT_A = XIN + 8 * XIN_CH;
  float* HOUT_B = HOUT_A + 8 * HOUT_CH;
  float* MV     = HOUT_B + 8 * HOUT_CH;
  size_t needed = (size_t)((MV + 4 * MV_CH) - ws) * 4;
  if (ws_size < needed) return;

  // ---- 1. fused phase-A projections ----
  {
    Proj8 pc{};
    const int* idv[8] = {p_ids, p_ids, h_ids, h_ids, cp_ids, cp_ids, ch_ids, ch_ids};
    for (int c = 0; c < 8; ++c) {
      int word = c < 4;
      pc.c[c].ids = idv[c];
      pc.c[c].emb = word ? word_emb : char_emb;
      pc.c[c].src = nullptr;
      pc.c[c].W    = word ? ((c & 1) ? ctx_Wih_b : ctx_Wih_f) : ((c & 1) ? chr_Wih_b : chr_Wih_f);
      pc.c[c].bias = word ? ((c & 1) ? ctx_b_b : ctx_b_f)     : ((c & 1) ? chr_b_b : chr_b_f);
      pc.c[c].out = XIN + c * XIN_CH;
      pc.c[c].rev = c & 1;
      pc.c[c].K = word ? 300 : 50;
      pc.c[c].ksteps = word ? 10 : 2;
    }
    k_proj<<<8 * Sz * NBK, 256, 0, stream>>>(pc);
  }
  // ---- 2. phase-A LSTMs ----
  {
    Lstm8 la{};
    for (int c = 0; c < 8; ++c) {
      la.c[c].xin = XIN + c * XIN_CH;
      la.c[c].Whh = (c < 4) ? ((c & 1) ? ctx_Whh_b : ctx_Whh_f)
                            : ((c & 1) ? chr_Whh_b : chr_Whh_f);
      la.c[c].hout = HOUT_A + c * HOUT_CH;
      la.c[c].rev = c & 1;
      la.c[c].store_all = 1;
    }
    k_lstm<<<8, 1024, 0, stream>>>(la);
  }
  // ---- 3-5. branch ----
  k_att4<<<4 * Bz * 64, 256, 0, stream>>>(HOUT_A, ATT4);
  k_feats4<<<4 * 2 * Bz * Sz, 128, 0, stream>>>(ATT4, HOUT_A, FEAT4);
  {
    MatchArgs m{};
    m.houtA = HOUT_A; m.feat4 = FEAT4; m.mv = MV;
    m.w_full[0] = mp_w1; m.w_full[1] = mp_w2; m.w_full[2] = char_w1; m.w_full[3] = char_w2;
    m.w3 = mp_w3; m.w4 = mp_w4; m.w5 = mp_w5; m.w6 = mp_w6;
    k_match24<<<4 * 6 * 160, 256, 0, stream>>>(m);
  }
  // ---- 6. phase-B projections (K=120) ----
  {
    Proj8 pa{};
    for (int c = 0; c < 8; ++c) {
      pa.c[c].ids = nullptr; pa.c[c].emb = nullptr;
      pa.c[c].src = MV + (c >> 1) * MV_CH;
      pa.c[c].W = (c & 1) ? agg_Wih_b : agg_Wih_f;
      pa.c[c].bias = (c & 1) ? agg_b_b : agg_b_f;
      pa.c[c].out = XIN + c * XIN_CH;
      pa.c[c].rev = c & 1;
      pa.c[c].K = 120;
      pa.c[c].ksteps = 4;
    }
    k_proj<<<8 * Sz * NBK, 256, 0, stream>>>(pa);
  }
  // ---- 7. phase-B LSTMs ----
  {
    Lstm8 la{};
    for (int c = 0; c < 8; ++c) {
      la.c[c].xin = XIN + c * XIN_CH;
      la.c[c].Whh = (c & 1) ? agg_Whh_b : agg_Whh_f;
      la.c[c].hout = HOUT_B + c * HOUT_CH;
      la.c[c].rev = c & 1;
      la.c[c].store_all = 0;
    }
    k_lstm<<<8, 1024, 0, stream>>>(la);
  }
  // ---- 8. fused head ----
  k_head<<<Bz, 1024, 0, stream>>>(HOUT_B, hw_lin_w, hw_lin_b, hw_gate_w, hw_gate_b,
                                  fc1_w, fc1_b, fc2_w, fc2_b, (float*)d_out);
}